// Round 6
// baseline (402.075 us; speedup 1.0000x reference)
//
#include <hip/hip_runtime.h>
#include <math.h>

#define N_USERS 50000
#define N_ITEMS 100000
#define N_ENT   200000
#define N_NODES (N_USERS + N_ITEMS)
#define N_REL   32
#define DIM     64

#define NB_KG  391          // KG buckets: dst>>9 (512 keys each)
#define NB_UI  586          // UI buckets: row>>8 (256 keys each)
#define NB_TOT (NB_KG + NB_UI)   // 977
#define CAPD   4096         // max KEPT edges per bucket (post-filter)

__device__ __forceinline__ unsigned short f2bf(float f) {   // RNE f32->bf16
    unsigned u = __float_as_uint(f);
    u += 0x7FFFu + ((u >> 16) & 1u);
    return (unsigned short)(u >> 16);
}
__device__ __forceinline__ float bf_lo(unsigned v) { return __uint_as_float(v << 16); }
__device__ __forceinline__ float bf_hi(unsigned v) { return __uint_as_float(v & 0xFFFF0000u); }
__device__ __forceinline__ int getbit(const unsigned* m, int i) {
    return (m[i >> 5] >> (i & 31)) & 1;
}

// ---------------------------------------------------------------------------
// ent_matmul: y16 = bf16(x @ W^T) — NO-LDS form.
// Old LDS version: 51.2KB tiles -> 12% occupancy, 4.2M staging bank-conflict
// cycles (transpose writes at k-stride 528 dwords = 16 mod 32 — structurally
// unfixable with float4-aligned rows), 2 barriers. This version reads x and w
// rows straight from global per k-chunk: same-address lanes broadcast, L1
// serves the 8x/16x block-level redundancy; HBM traffic unchanged.
// FMA order (k ascending, one element at a time) is BIT-IDENTICAL to the
// LDS version, so absmax is unchanged.
// ---------------------------------------------------------------------------
__global__ __launch_bounds__(128) void ent_matmul(const float* __restrict__ x,
                                                  const float* __restrict__ w,
                                                  unsigned short* __restrict__ y16,
                                                  int n_ent) {
    int tid  = threadIdx.x;
    int base = blockIdx.x * 128;
    int j0 = (tid & 7) * 8;          // 8 output cols
    int r0 = base + (tid >> 3) * 8;  // 8 rows
    const float4* x4 = (const float4*)x;
    const float4* w4 = (const float4*)w;

    float acc[8][8];
    #pragma unroll
    for (int i = 0; i < 8; i++)
        #pragma unroll
        for (int j = 0; j < 8; j++) acc[i][j] = 0.f;

    bool full = (r0 + 8 <= n_ent);
    #pragma unroll 2
    for (int kc = 0; kc < 16; kc++) {        // k-chunk of 4
        float4 wr[8], xr[8];
        #pragma unroll
        for (int jj = 0; jj < 8; jj++)
            wr[jj] = w4[(j0 + jj) * 16 + kc];          // w[j][4kc..4kc+3]
        if (full) {
            #pragma unroll
            for (int i = 0; i < 8; i++)
                xr[i] = x4[(long)(r0 + i) * 16 + kc];  // x[r][4kc..4kc+3]
        } else {
            #pragma unroll
            for (int i = 0; i < 8; i++)
                xr[i] = (r0 + i < n_ent) ? x4[(long)(r0 + i) * 16 + kc]
                                         : make_float4(0.f, 0.f, 0.f, 0.f);
        }
        #pragma unroll
        for (int i = 0; i < 8; i++)
            #pragma unroll
            for (int jj = 0; jj < 8; jj++) {
                acc[i][jj] += xr[i].x * wr[jj].x;
                acc[i][jj] += xr[i].y * wr[jj].y;
                acc[i][jj] += xr[i].z * wr[jj].z;
                acc[i][jj] += xr[i].w * wr[jj].w;
            }
    }

    #pragma unroll
    for (int i = 0; i < 8; i++) {
        int gr = r0 + i;
        if (gr < n_ent) {
            uint4 o;
            o.x = (unsigned)f2bf(acc[i][0]) | ((unsigned)f2bf(acc[i][1]) << 16);
            o.y = (unsigned)f2bf(acc[i][2]) | ((unsigned)f2bf(acc[i][3]) << 16);
            o.z = (unsigned)f2bf(acc[i][4]) | ((unsigned)f2bf(acc[i][5]) << 16);
            o.w = (unsigned)f2bf(acc[i][6]) | ((unsigned)f2bf(acc[i][7]) << 16);
            *(uint4*)&y16[(long)gr * 64 + j0] = o;
        }
    }
}

// ---------------------------------------------------------------------------
// build_masks: membership bitmaps + zero bcnt.
// ---------------------------------------------------------------------------
__global__ __launch_bounds__(256) void build_masks(const int* __restrict__ i2e,
                                                   const int* __restrict__ u,
                                                   const int* __restrict__ ipos,
                                                   const int* __restrict__ ineg,
                                                   unsigned* __restrict__ ent_mask,
                                                   unsigned* __restrict__ node_mask,
                                                   int* __restrict__ bcnt,
                                                   int B) {
    int t = blockIdx.x * 256 + threadIdx.x;
    int stride = gridDim.x * 256;
    for (int i = threadIdx.x; i < NB_TOT; i += 256) bcnt[i] = 0;
    for (int i = t; i < N_ITEMS; i += stride) {
        int e = i2e[i];
        atomicOr(&ent_mask[e >> 5], 1u << (e & 31));
    }
    for (int i = t; i < 3 * B; i += stride) {
        int r = (i < B) ? u[i]
              : (i < 2 * B) ? N_USERS + ipos[i - B]
                            : N_USERS + ineg[i - 2 * B];
        atomicOr(&node_mask[r >> 5], 1u << (r & 31));
    }
}

// ---------------------------------------------------------------------------
// Pass A: per-block LDS bucket histogram over KEPT edges only.
// Block 0 additionally precomputes the sigmoid gate table ONCE into gateg.
// ---------------------------------------------------------------------------
__global__ __launch_bounds__(256) void bucket_hist(const int* __restrict__ kg_dst,
                                                   const int* __restrict__ ui_row,
                                                   const unsigned* __restrict__ ent_mask,
                                                   const unsigned* __restrict__ node_mask,
                                                   const float* __restrict__ rel_emb,
                                                   float2* __restrict__ gateg,
                                                   int* __restrict__ bcnt,
                                                   int e_kg, int e_ui) {
    __shared__ int h[NB_TOT];
    for (int i = threadIdx.x; i < NB_TOT; i += 256) h[i] = 0;
    __syncthreads();
    if (blockIdx.x == 0) {
        for (int idx = threadIdx.x; idx < N_REL * 32; idx += 256) {
            int rel = idx >> 5, hl2 = idx & 31;
            float g0 = 1.0f / (1.0f + __expf(-rel_emb[rel * 64 + 2 * hl2]));
            float g1 = 1.0f / (1.0f + __expf(-rel_emb[rel * 64 + 2 * hl2 + 1]));
            gateg[idx] = make_float2(g0, g1);
        }
    }
    int n = e_kg + e_ui;
    int t = blockIdx.x * 256 + threadIdx.x;
    int stride = gridDim.x * 256;
    for (int e = t; e < n; e += stride) {
        int bk;
        if (e < e_kg) {
            int d = kg_dst[e];
            if (!getbit(ent_mask, d)) continue;
            bk = d >> 9;
        } else {
            int r = ui_row[e - e_kg];
            if (!getbit(node_mask, r)) continue;
            bk = NB_KG + (r >> 8);
        }
        atomicAdd(&h[bk], 1);
    }
    __syncthreads();
    for (int i = threadIdx.x; i < NB_TOT; i += 256)
        if (h[i]) atomicAdd(&bcnt[i], h[i]);
}

// ---------------------------------------------------------------------------
// Pass B: exclusive scan of bucket counts. boff[NB] = total KEPT edges.
// ---------------------------------------------------------------------------
__global__ __launch_bounds__(256) void bucket_scan(const int* __restrict__ bcnt,
                                                   int* __restrict__ boff_kg,
                                                   int* __restrict__ boff_ui,
                                                   int* __restrict__ bcur) {
    __shared__ int sh[1024];
    int t = threadIdx.x;
    for (int seg = 0; seg < 2; seg++) {
        int NB = seg ? NB_UI : NB_KG;
        const int* src = bcnt + (seg ? NB_KG : 0);
        int idx[4] = { t, t + 256, t + 512, t + 768 };
        int v[4];
        #pragma unroll
        for (int q = 0; q < 4; q++) {
            v[q] = (idx[q] < NB) ? src[idx[q]] : 0;
            sh[idx[q]] = v[q];
        }
        __syncthreads();
        for (int o = 1; o < 1024; o <<= 1) {
            int a[4];
            #pragma unroll
            for (int q = 0; q < 4; q++) a[q] = (idx[q] >= o) ? sh[idx[q] - o] : 0;
            __syncthreads();
            #pragma unroll
            for (int q = 0; q < 4; q++) sh[idx[q]] += a[q];
            __syncthreads();
        }
        int* boff = seg ? boff_ui : boff_kg;
        int  base = seg ? NB_KG : 0;
        #pragma unroll
        for (int q = 0; q < 4; q++) {
            if (idx[q] < NB) {
                int ex = sh[idx[q]] - v[q];
                boff[idx[q]] = ex;
                bcur[base + idx[q]] = ex;
                if (idx[q] == NB - 1) boff[NB] = sh[idx[q]];
            }
        }
        __syncthreads();
    }
}

// ---------------------------------------------------------------------------
// Pass C: scatter KEPT edges into bucket regions.
// CHUNK 1024 (4/thread), grid 2048 -> 8 blocks/CU (was 4096/512 -> 2
// blocks/CU, 18% occupancy, latency-bound at 4% VALUBusy).
// ---------------------------------------------------------------------------
__global__ __launch_bounds__(256) void bucket_scatter(const int* __restrict__ kg_src,
                                                      const int* __restrict__ kg_dst,
                                                      const int* __restrict__ kg_rel,
                                                      const int* __restrict__ ui_row,
                                                      const int* __restrict__ ui_col,
                                                      const float* __restrict__ ui_vals,
                                                      const unsigned* __restrict__ ent_mask,
                                                      const unsigned* __restrict__ node_mask,
                                                      int* __restrict__ bcur,
                                                      unsigned int* __restrict__ kgrec,
                                                      int* __restrict__ uirec,
                                                      float* __restrict__ uval,
                                                      int e_kg, int e_ui) {
    __shared__ int h[NB_TOT];
    __shared__ int lbase[NB_TOT];
    int n = e_kg + e_ui;
    int nchunks = (n + 1023) >> 10;
    int tid = threadIdx.x;
    for (int c = blockIdx.x; c < nchunks; c += gridDim.x) {
        int base = c << 10;
        for (int i = tid; i < NB_TOT; i += 256) h[i] = 0;
        __syncthreads();
        unsigned int rec[4];
        float val[4];
        int bk[4];
        #pragma unroll
        for (int j = 0; j < 4; j++) {
            int e = base + j * 256 + tid;
            bk[j] = -1;
            if (e < n) {
                if (e < e_kg) {
                    int d = kg_dst[e];
                    if (getbit(ent_mask, d)) {
                        bk[j]  = d >> 9;
                        rec[j] = (unsigned int)kg_src[e] | ((unsigned int)kg_rel[e] << 18)
                                 | ((unsigned int)(d & 511) << 23);
                        atomicAdd(&h[bk[j]], 1);
                    }
                } else {
                    int i2 = e - e_kg;
                    int r  = ui_row[i2];
                    if (getbit(node_mask, r)) {
                        bk[j]  = NB_KG + (r >> 8);
                        rec[j] = (unsigned int)ui_col[i2] | ((unsigned int)(r & 255) << 18);
                        val[j] = ui_vals[i2];
                        atomicAdd(&h[bk[j]], 1);
                    }
                }
            }
        }
        __syncthreads();
        for (int i = tid; i < NB_TOT; i += 256) {
            int cc = h[i];
            lbase[i] = cc ? atomicAdd(&bcur[i], cc) : 0;
        }
        __syncthreads();
        #pragma unroll
        for (int j = 0; j < 4; j++) {
            if (bk[j] >= 0) {
                int pos = atomicAdd(&lbase[bk[j]], 1);
                if (bk[j] < NB_KG) kgrec[pos] = rec[j];
                else               { uirec[pos] = (int)rec[j]; uval[pos] = val[j]; }
            }
        }
        __syncthreads();
    }
}

// ---------------------------------------------------------------------------
// Pass D: one block per bucket. LDS counting-sort of KEPT records.
// ---------------------------------------------------------------------------
__global__ __launch_bounds__(256) void bucket_finalize(const int* __restrict__ boff_kg,
                                                       const int* __restrict__ boff_ui,
                                                       unsigned int* __restrict__ kgrec,
                                                       int* __restrict__ uirec,
                                                       float* __restrict__ uval,
                                                       int* __restrict__ off_kg,
                                                       int* __restrict__ off_ui) {
    __shared__ unsigned int rec[CAPD];
    __shared__ float fval[CAPD];
    __shared__ int hist[512];
    bool iskg = blockIdx.x < NB_KG;
    int  b    = iskg ? blockIdx.x : blockIdx.x - NB_KG;
    const int* boff = iskg ? boff_kg : boff_ui;
    int ebeg = boff[b], eend = boff[b + 1];
    int ne   = min(eend - ebeg, CAPD);
    int key_base = iskg ? (b << 9) : (b << 8);
    int nkeys = iskg ? min(512, N_ENT - key_base) : min(256, N_NODES - key_base);
    int SH = iskg ? 23 : 18;
    int tid = threadIdx.x;

    for (int i = tid; i < ne; i += 256) {
        if (iskg) rec[i] = kgrec[ebeg + i];
        else { rec[i] = (unsigned int)uirec[ebeg + i]; fval[i] = uval[ebeg + i]; }
    }
    for (int i = tid; i < 512; i += 256) hist[i] = 0;
    __syncthreads();
    for (int i = tid; i < ne; i += 256)
        atomicAdd(&hist[rec[i] >> SH], 1);
    __syncthreads();
    int i0 = tid, i1 = tid + 256;
    int v0 = hist[i0], v1 = hist[i1];
    __syncthreads();
    for (int o = 1; o < 512; o <<= 1) {
        int a0 = (i0 >= o) ? hist[i0 - o] : 0;
        int a1 = (i1 >= o) ? hist[i1 - o] : 0;
        __syncthreads();
        hist[i0] += a0; hist[i1] += a1;
        __syncthreads();
    }
    int e0 = hist[i0] - v0, e1 = hist[i1] - v1;
    __syncthreads();
    hist[i0] = e0; hist[i1] = e1;
    int* offg = iskg ? off_kg : off_ui;
    if (i0 < nkeys) offg[key_base + i0] = ebeg + e0;
    if (i1 < nkeys) offg[key_base + i1] = ebeg + e1;
    if (blockIdx.x == 0 && tid == 0) {
        off_kg[N_ENT]   = boff_kg[NB_KG];
        off_ui[N_NODES] = boff_ui[NB_UI];
    }
    __syncthreads();
    for (int i = tid; i < ne; i += 256) {
        unsigned int r = rec[i];
        int k = r >> SH;
        int slot = atomicAdd(&hist[k], 1);
        if (iskg) kgrec[ebeg + slot] = r & 0x7FFFFFu;
        else      { uirec[ebeg + slot] = (int)(r & 0x3FFFFu); uval[ebeg + slot] = fval[i]; }
    }
}

// ---------------------------------------------------------------------------
// kgagg_build: TWO NODES PER WAVE, one per half-wave (32 lanes).
// Half layout: 16 lanes x uint2 per row (dims 4ql..4ql+3), 2 edge slots.
// ---------------------------------------------------------------------------
__global__ __launch_bounds__(256) void kgagg_build(const int* __restrict__ off,
                                                   const unsigned int* __restrict__ packed,
                                                   const unsigned short* __restrict__ y16,
                                                   const float* __restrict__ entity_emb,
                                                   const float* __restrict__ user_emb,
                                                   const int* __restrict__ i2e,
                                                   const float4* __restrict__ gate4,
                                                   float* __restrict__ all_emb,
                                                   unsigned short* __restrict__ all16) {
    int lane = threadIdx.x & 63;
    int half = lane >> 5;          // which node of the pair
    int hl   = lane & 31;
    int duo  = hl >> 4;            // edge slot within half
    int ql   = hl & 15;            // dims 4ql..4ql+3
    long wpair = (long)((blockIdx.x * 256 + threadIdx.x) >> 6);
    int w = (int)(wpair * 2 + half);
    if (w >= N_NODES) return;      // N_NODES even: whole wave exits together

    if (w < N_USERS) {             // both halves users: bf16 copy only
        if (duo == 0) {
            float4 v = ((const float4*)user_emb)[(long)w * 16 + ql];
            ((uint2*)all16)[(long)w * 16 + ql] =
                make_uint2((unsigned)f2bf(v.x) | ((unsigned)f2bf(v.y) << 16),
                           (unsigned)f2bf(v.z) | ((unsigned)f2bf(v.w) << 16));
        }
        return;
    }

    int ent = i2e[w - N_USERS];    // half-uniform (broadcast load)
    const uint2* y2 = (const uint2*)y16;
    int beg = off[ent], end = off[ent + 1];
    float a0 = 0.f, a1 = 0.f, a2 = 0.f, a3 = 0.f;
    float b0 = 0.f, b1 = 0.f, b2 = 0.f, b3 = 0.f;
    int p = beg;
    for (; p + 4 <= end; p += 4) {     // 4 edges per half per iter
        unsigned pk0 = packed[p + duo];
        unsigned pk1 = packed[p + 2 + duo];
        uint2 v0 = y2[(long)(pk0 & 0x3FFFF) * 16 + ql];
        uint2 v1 = y2[(long)(pk1 & 0x3FFFF) * 16 + ql];
        float4 g0 = gate4[(pk0 >> 18) * 16 + ql];
        float4 g1 = gate4[(pk1 >> 18) * 16 + ql];
        a0 += bf_lo(v0.x) * g0.x;  a1 += bf_hi(v0.x) * g0.y;
        a2 += bf_lo(v0.y) * g0.z;  a3 += bf_hi(v0.y) * g0.w;
        b0 += bf_lo(v1.x) * g1.x;  b1 += bf_hi(v1.x) * g1.y;
        b2 += bf_lo(v1.y) * g1.z;  b3 += bf_hi(v1.y) * g1.w;
    }
    if (p + duo < end) {               // tail edges p..p+1
        unsigned pk = packed[p + duo];
        uint2 v = y2[(long)(pk & 0x3FFFF) * 16 + ql];
        float4 g = gate4[(pk >> 18) * 16 + ql];
        a0 += bf_lo(v.x) * g.x;  a1 += bf_hi(v.x) * g.y;
        a2 += bf_lo(v.y) * g.z;  a3 += bf_hi(v.y) * g.w;
    }
    if (p + 2 + duo < end) {           // tail edge p+2 (p+3 impossible)
        unsigned pk = packed[p + 2 + duo];
        uint2 v = y2[(long)(pk & 0x3FFFF) * 16 + ql];
        float4 g = gate4[(pk >> 18) * 16 + ql];
        b0 += bf_lo(v.x) * g.x;  b1 += bf_hi(v.x) * g.y;
        b2 += bf_lo(v.y) * g.z;  b3 += bf_hi(v.y) * g.w;
    }
    a0 += b0; a1 += b1; a2 += b2; a3 += b3;
    a0 += __shfl_xor(a0, 16);          // merge the two duo slots (within half)
    a1 += __shfl_xor(a1, 16);
    a2 += __shfl_xor(a2, 16);
    a3 += __shfl_xor(a3, 16);

    float deg = fmaxf((float)(end - beg), 1.0f);
    float4 xv = ((const float4*)entity_emb)[(long)ent * 16 + ql];
    float v0 = a0 / deg + xv.x;
    float v1 = a1 / deg + xv.y;
    float v2 = a2 / deg + xv.z;
    float v3 = a3 / deg + xv.w;
    v0 = (v0 > 0.0f) ? v0 : (__expf(v0) - 1.0f);
    v1 = (v1 > 0.0f) ? v1 : (__expf(v1) - 1.0f);
    v2 = (v2 > 0.0f) ? v2 : (__expf(v2) - 1.0f);
    v3 = (v3 > 0.0f) ? v3 : (__expf(v3) - 1.0f);
    float ss = v0 * v0 + v1 * v1 + v2 * v2 + v3 * v3;
    ss += __shfl_xor(ss, 1);
    ss += __shfl_xor(ss, 2);
    ss += __shfl_xor(ss, 4);
    ss += __shfl_xor(ss, 8);
    float inv = 1.0f / fmaxf(sqrtf(ss), 1e-12f);
    if (duo == 0) {
        float r0 = v0 * inv, r1 = v1 * inv, r2 = v2 * inv, r3 = v3 * inv;
        ((float4*)all_emb)[(long)w * 16 + ql] = make_float4(r0, r1, r2, r3);
        ((uint2*)all16)[(long)w * 16 + ql] =
            make_uint2((unsigned)f2bf(r0) | ((unsigned)f2bf(r1) << 16),
                       (unsigned)f2bf(r2) | ((unsigned)f2bf(r3) << 16));
    }
}

// ---------------------------------------------------------------------------
// ui_aggregate_s: TWO SAMPLE ROWS PER WAVE (same half-wave transform).
// ---------------------------------------------------------------------------
__global__ __launch_bounds__(256) void ui_aggregate_s(const int* __restrict__ off,
                                                      const int* __restrict__ colrec,
                                                      const float* __restrict__ uval,
                                                      const float* __restrict__ all_emb,
                                                      const float* __restrict__ user_emb,
                                                      const unsigned short* __restrict__ all16,
                                                      const int* __restrict__ u,
                                                      const int* __restrict__ ipos,
                                                      const int* __restrict__ ineg,
                                                      float* __restrict__ final_emb, int B) {
    const uint2* a2p = (const uint2*)all16;
    int lane = threadIdx.x & 63;
    int half = lane >> 5;
    int hl   = lane & 31;
    int duo  = hl >> 4;
    int ql   = hl & 15;
    long wpair = (long)((blockIdx.x * 256 + threadIdx.x) >> 6);
    int s = (int)(wpair * 2 + half);
    if (s >= 3 * B) return;            // 3B even: whole wave exits together
    int r;
    if (s < B)          r = u[s];
    else if (s < 2 * B) r = N_USERS + ipos[s - B];
    else                r = N_USERS + ineg[s - 2 * B];

    int beg = off[r], end = off[r + 1];
    float a0 = 0.f, a1 = 0.f, a2 = 0.f, a3 = 0.f;
    float b0 = 0.f, b1 = 0.f, b2 = 0.f, b3 = 0.f;
    int p = beg;
    for (; p + 4 <= end; p += 4) {
        int   c0 = colrec[p + duo];
        int   c1 = colrec[p + 2 + duo];
        float d0 = uval[p + duo];
        float d1 = uval[p + 2 + duo];
        uint2 v0 = a2p[(long)c0 * 16 + ql];
        uint2 v1 = a2p[(long)c1 * 16 + ql];
        a0 += d0 * bf_lo(v0.x);  a1 += d0 * bf_hi(v0.x);
        a2 += d0 * bf_lo(v0.y);  a3 += d0 * bf_hi(v0.y);
        b0 += d1 * bf_lo(v1.x);  b1 += d1 * bf_hi(v1.x);
        b2 += d1 * bf_lo(v1.y);  b3 += d1 * bf_hi(v1.y);
    }
    if (p + duo < end) {
        int   c = colrec[p + duo];
        float d = uval[p + duo];
        uint2 v = a2p[(long)c * 16 + ql];
        a0 += d * bf_lo(v.x);  a1 += d * bf_hi(v.x);
        a2 += d * bf_lo(v.y);  a3 += d * bf_hi(v.y);
    }
    if (p + 2 + duo < end) {
        int   c = colrec[p + 2 + duo];
        float d = uval[p + 2 + duo];
        uint2 v = a2p[(long)c * 16 + ql];
        b0 += d * bf_lo(v.x);  b1 += d * bf_hi(v.x);
        b2 += d * bf_lo(v.y);  b3 += d * bf_hi(v.y);
    }
    a0 += b0; a1 += b1; a2 += b2; a3 += b3;
    a0 += __shfl_xor(a0, 16);
    a1 += __shfl_xor(a1, 16);
    a2 += __shfl_xor(a2, 16);
    a3 += __shfl_xor(a3, 16);
    if (duo == 0) {
        float4 ae = (r < N_USERS)
            ? ((const float4*)user_emb)[(long)r * 16 + ql]
            : ((const float4*)all_emb)[(long)r * 16 + ql];
        ((float4*)final_emb)[(long)r * 16 + ql] =
            make_float4(0.5f * (ae.x + a0), 0.5f * (ae.y + a1),
                        0.5f * (ae.z + a2), 0.5f * (ae.w + a3));
    }
}

// ---------------------------------------------------------------------------
// Epilogue (intent folded in): one wave per sample.
// ---------------------------------------------------------------------------
__global__ void final_kernel(const int* __restrict__ u, const int* __restrict__ ipos,
                             const int* __restrict__ ineg,
                             const float* __restrict__ final_emb,
                             const float* __restrict__ all_emb,
                             const float* __restrict__ rw, const float* __restrict__ rb,
                             const float* __restrict__ iw, const float* __restrict__ rel_emb,
                             float* __restrict__ out, int B) {
    __shared__ float sh_intent[128];
    if (threadIdx.x < 64) {
        int j = threadIdx.x;
        for (int k = 0; k < 2; k++) {
            float m = -1e30f;
            for (int r = 0; r < N_REL; r++) m = fmaxf(m, iw[k * N_REL + r]);
            float Z = 0.f, acc = 0.f;
            for (int r = 0; r < N_REL; r++) {
                float e = __expf(iw[k * N_REL + r] - m);
                Z += e;
                acc += e * rel_emb[r * 64 + j];
            }
            sh_intent[k * 64 + j] = acc / Z;
        }
    }
    __syncthreads();
    int lane = threadIdx.x & 63;
    int wave = (blockIdx.x * blockDim.x + threadIdx.x) >> 6;
    int nw   = (gridDim.x * blockDim.x) >> 6;
    for (int b = wave; b < B; b += nw) {
        int uu = u[b];
        float up = final_emb[(long)uu * 64 + lane];
        float l0 = up * rw[lane];
        float l1 = up * rw[64 + lane];
        #pragma unroll
        for (int o = 32; o; o >>= 1) {
            l0 += __shfl_xor(l0, o);
            l1 += __shfl_xor(l1, o);
        }
        l0 += rb[0]; l1 += rb[1];
        float m  = fmaxf(l0, l1);
        float e0 = __expf(l0 - m), e1 = __expf(l1 - m);
        float inv = 1.0f / (e0 + e1);
        float p0 = e0 * inv, p1 = e1 * inv;
        float ue = up + p0 * sh_intent[lane] + p1 * sh_intent[64 + lane];

        int it = ipos[b];
        long rr = (long)(N_USERS + it) * 64 + lane;
        float ie = final_emb[rr] + all_emb[rr];
        float dp = ue * ie;
        #pragma unroll
        for (int o = 32; o; o >>= 1) dp += __shfl_xor(dp, o);
        if (lane == 0) out[b] = dp;

        it = ineg[b];
        rr = (long)(N_USERS + it) * 64 + lane;
        ie = final_emb[rr] + all_emb[rr];
        dp = ue * ie;
        #pragma unroll
        for (int o = 32; o; o >>= 1) dp += __shfl_xor(dp, o);
        if (lane == 0) out[B + b] = dp;
    }
}

extern "C" void kernel_launch(void* const* d_in, const int* in_sizes, int n_in,
                              void* d_out, int out_size, void* d_ws, size_t ws_size,
                              hipStream_t stream) {
    const int*   u          = (const int*)  d_in[0];
    const int*   ipos       = (const int*)  d_in[1];
    const int*   ineg       = (const int*)  d_in[2];
    const float* user_emb   = (const float*)d_in[3];
    const float* entity_emb = (const float*)d_in[4];
    const float* rel_emb    = (const float*)d_in[5];
    const float* iw         = (const float*)d_in[6];
    const float* rw         = (const float*)d_in[7];
    const float* rb         = (const float*)d_in[8];
    const float* kgw        = (const float*)d_in[9];
    const float* ui_vals    = (const float*)d_in[10];
    const int*   i2e        = (const int*)  d_in[11];
    const int*   kg_src     = (const int*)  d_in[12];
    const int*   kg_dst     = (const int*)  d_in[13];
    const int*   kg_rel     = (const int*)  d_in[14];
    const int*   ui_row     = (const int*)  d_in[15];
    const int*   ui_col     = (const int*)  d_in[16];
    float*       out        = (float*)d_out;

    int B    = in_sizes[0];
    int e_kg = in_sizes[12];
    int e_ui = in_sizes[15];

    // ---------------- workspace layout (bytes) ----------------
    char* ws = (char*)d_ws;
    unsigned short* y16       = (unsigned short*)(ws + 0);        // 25.6 MB
    float*          all_emb   = (float*)(ws + 25600000);          // 38.4 MB
    unsigned short* all16     = (unsigned short*)(ws + 64000000); // 19.2 MB
    float*          final_emb = (float*)(ws + 83200000);          // 38.4 MB (sparse use)
    unsigned int*   kgrec     = (unsigned int*)(ws + 121600000);  // 8 MB
    int*            uirec     = (int*)(ws + 129600000);           // 4 MB
    float*          uval      = (float*)(ws + 133600000);         // 4 MB
    int*            off_kg    = (int*)(ws + 137600000);           // 200001 ints
    int*            off_ui    = (int*)(ws + 138400256);           // 150001 ints
    unsigned*       ent_mask  = (unsigned*)(ws + 139000512);      // 25088 B (200K bits)
    unsigned*       node_mask = (unsigned*)(ws + 139025600);      // 18752 B (150K bits)
    int*            bcnt      = (int*)(ws + 139600512);           // 977 ints
    int*            boff_kg   = (int*)(ws + 139604480);           // 392 ints
    int*            boff_ui   = (int*)(ws + 139606272);           // 587 ints
    int*            bcur      = (int*)(ws + 139608704);           // 977 ints
    float2*         gateg     = (float2*)(ws + 139612672);        // 8 KB gate table

    hipMemsetAsync(ent_mask, 0, 25088 + 18752, stream);   // masks contiguous
    build_masks    <<<512, 256, 0, stream>>>(i2e, u, ipos, ineg, ent_mask, node_mask,
                                             bcnt, B);
    bucket_hist    <<<1024, 256, 0, stream>>>(kg_dst, ui_row, ent_mask, node_mask,
                                              rel_emb, gateg, bcnt, e_kg, e_ui);
    bucket_scan    <<<1,   256, 0, stream>>>(bcnt, boff_kg, boff_ui, bcur);
    bucket_scatter <<<2048, 256, 0, stream>>>(kg_src, kg_dst, kg_rel, ui_row, ui_col,
                                              ui_vals, ent_mask, node_mask,
                                              bcur, kgrec, uirec, uval, e_kg, e_ui);
    bucket_finalize<<<NB_TOT, 256, 0, stream>>>(boff_kg, boff_ui, kgrec, uirec, uval,
                                                off_kg, off_ui);

    ent_matmul <<<(N_ENT + 127) / 128, 128, 0, stream>>>(entity_emb, kgw, y16, N_ENT);
    {   // two nodes per wave
        int nwaves = (N_NODES + 1) / 2;
        int nblk   = (nwaves * 64 + 255) / 256;
        kgagg_build<<<nblk, 256, 0, stream>>>(
            off_kg, kgrec, y16, entity_emb, user_emb, i2e, (const float4*)gateg,
            all_emb, all16);
    }
    {   // two sample rows per wave
        int nwaves = (3 * B + 1) / 2;
        int nblk   = (nwaves * 64 + 255) / 256;
        ui_aggregate_s<<<nblk, 256, 0, stream>>>(
            off_ui, uirec, uval, all_emb, user_emb, all16, u, ipos, ineg, final_emb, B);
    }
    final_kernel<<<256, 256, 0, stream>>>(u, ipos, ineg, final_emb, all_emb,
                                          rw, rb, iw, rel_emb, out, B);
}

// Round 7
// 360.134 us; speedup vs baseline: 1.1165x; 1.1165x over previous
//
#include <hip/hip_runtime.h>
#include <math.h>

#define N_USERS 50000
#define N_ITEMS 100000
#define N_ENT   200000
#define N_NODES (N_USERS + N_ITEMS)
#define N_REL   32
#define DIM     64

#define NB_KG  391          // KG buckets: dst>>9 (512 keys each)
#define NB_UI  586          // UI buckets: row>>8 (256 keys each)
#define NB_TOT (NB_KG + NB_UI)   // 977
#define CAPD   4096         // max KEPT edges per bucket (post-filter)

__device__ __forceinline__ unsigned short f2bf(float f) {   // RNE f32->bf16
    unsigned u = __float_as_uint(f);
    u += 0x7FFFu + ((u >> 16) & 1u);
    return (unsigned short)(u >> 16);
}
__device__ __forceinline__ float bf_lo(unsigned v) { return __uint_as_float(v << 16); }
__device__ __forceinline__ float bf_hi(unsigned v) { return __uint_as_float(v & 0xFFFF0000u); }
__device__ __forceinline__ int getbit(const unsigned* m, int i) {
    return (m[i >> 5] >> (i & 31)) & 1;
}

// ---------------------------------------------------------------------------
// ent_matmul: y16 = bf16(x @ W^T), LDS GEMM with XOR-swizzled tiles.
// R5's LDS form had 4.2M bank-conflict cycles in the staging transpose
// (structural: banks = 16(k4&1)+4c+r -> 8-way). Swizzle sigma(kk)=kk&28
// (XOR into the row index, bits 2-4) spreads each store across all 32 banks
// (2 lanes/bank = free). Pads dropped: xt[64][128]+wt[64][64] = 48KB.
// float4 reads stay aligned (r0 mult of 8, swizzle bits 2-4, i in bits 0-1).
// FMA order is BIT-IDENTICAL to R5/R6 forms.
// ---------------------------------------------------------------------------
__global__ __launch_bounds__(128) void ent_matmul(const float* __restrict__ x,
                                                  const float* __restrict__ w,
                                                  unsigned short* __restrict__ y16,
                                                  int n_ent) {
    __shared__ float xt[64][128];
    __shared__ float wt[64][64];
    int tid  = threadIdx.x;
    int base = blockIdx.x * 128;

    #pragma unroll
    for (int q = 0; q < 8; q++) {
        int idx = q * 128 + tid;
        int j = idx >> 4, k4 = idx & 15;
        int s0 = (k4 << 2) & 28;          // sigma for rows 4k4..4k4+3
        float4 v = ((const float4*)w)[idx];
        wt[4 * k4 + 0][j ^ s0] = v.x;
        wt[4 * k4 + 1][j ^ s0] = v.y;
        wt[4 * k4 + 2][j ^ s0] = v.z;
        wt[4 * k4 + 3][j ^ s0] = v.w;
    }
    #pragma unroll
    for (int q = 0; q < 16; q++) {
        int idx = q * 128 + tid;
        int r = idx >> 4, k4 = idx & 15;
        int gr = base + r;
        int s0 = (k4 << 2) & 28;
        if (gr < n_ent) {
            float4 v = ((const float4*)x)[(long)gr * 16 + k4];
            xt[4 * k4 + 0][r ^ s0] = v.x;
            xt[4 * k4 + 1][r ^ s0] = v.y;
            xt[4 * k4 + 2][r ^ s0] = v.z;
            xt[4 * k4 + 3][r ^ s0] = v.w;
        }
    }
    __syncthreads();

    int j0 = (tid & 7) * 8;
    int r0 = (tid >> 3) * 8;
    float acc[8][8];
    #pragma unroll
    for (int i = 0; i < 8; i++)
        #pragma unroll
        for (int j = 0; j < 8; j++) acc[i][j] = 0.f;

    #pragma unroll 4
    for (int k = 0; k < 64; k++) {
        int s = k & 28;
        float4 xa = *(const float4*)&xt[k][r0 ^ s];
        float4 xb = *(const float4*)&xt[k][(r0 + 4) ^ s];
        float4 wa = *(const float4*)&wt[k][j0 ^ s];
        float4 wb = *(const float4*)&wt[k][(j0 + 4) ^ s];
        float xr[8] = {xa.x, xa.y, xa.z, xa.w, xb.x, xb.y, xb.z, xb.w};
        float wr[8] = {wa.x, wa.y, wa.z, wa.w, wb.x, wb.y, wb.z, wb.w};
        #pragma unroll
        for (int i = 0; i < 8; i++)
            #pragma unroll
            for (int j = 0; j < 8; j++)
                acc[i][j] += xr[i] * wr[j];
    }

    #pragma unroll
    for (int i = 0; i < 8; i++) {
        int gr = base + r0 + i;
        if (gr < n_ent) {
            uint4 o;
            o.x = (unsigned)f2bf(acc[i][0]) | ((unsigned)f2bf(acc[i][1]) << 16);
            o.y = (unsigned)f2bf(acc[i][2]) | ((unsigned)f2bf(acc[i][3]) << 16);
            o.z = (unsigned)f2bf(acc[i][4]) | ((unsigned)f2bf(acc[i][5]) << 16);
            o.w = (unsigned)f2bf(acc[i][6]) | ((unsigned)f2bf(acc[i][7]) << 16);
            *(uint4*)&y16[(long)gr * 64 + j0] = o;
        }
    }
}

// ---------------------------------------------------------------------------
// build_masks: membership bitmaps + zero bcnt.
// ---------------------------------------------------------------------------
__global__ __launch_bounds__(256) void build_masks(const int* __restrict__ i2e,
                                                   const int* __restrict__ u,
                                                   const int* __restrict__ ipos,
                                                   const int* __restrict__ ineg,
                                                   unsigned* __restrict__ ent_mask,
                                                   unsigned* __restrict__ node_mask,
                                                   int* __restrict__ bcnt,
                                                   int B) {
    int t = blockIdx.x * 256 + threadIdx.x;
    int stride = gridDim.x * 256;
    for (int i = threadIdx.x; i < NB_TOT; i += 256) bcnt[i] = 0;
    for (int i = t; i < N_ITEMS; i += stride) {
        int e = i2e[i];
        atomicOr(&ent_mask[e >> 5], 1u << (e & 31));
    }
    for (int i = t; i < 3 * B; i += stride) {
        int r = (i < B) ? u[i]
              : (i < 2 * B) ? N_USERS + ipos[i - B]
                            : N_USERS + ineg[i - 2 * B];
        atomicOr(&node_mask[r >> 5], 1u << (r & 31));
    }
}

// ---------------------------------------------------------------------------
// Pass A: per-block LDS bucket histogram over KEPT edges only.
// Block 0 additionally precomputes the sigmoid gate table ONCE into gateg.
// ---------------------------------------------------------------------------
__global__ __launch_bounds__(256) void bucket_hist(const int* __restrict__ kg_dst,
                                                   const int* __restrict__ ui_row,
                                                   const unsigned* __restrict__ ent_mask,
                                                   const unsigned* __restrict__ node_mask,
                                                   const float* __restrict__ rel_emb,
                                                   float2* __restrict__ gateg,
                                                   int* __restrict__ bcnt,
                                                   int e_kg, int e_ui) {
    __shared__ int h[NB_TOT];
    for (int i = threadIdx.x; i < NB_TOT; i += 256) h[i] = 0;
    __syncthreads();
    if (blockIdx.x == 0) {
        for (int idx = threadIdx.x; idx < N_REL * 32; idx += 256) {
            int rel = idx >> 5, hl2 = idx & 31;
            float g0 = 1.0f / (1.0f + __expf(-rel_emb[rel * 64 + 2 * hl2]));
            float g1 = 1.0f / (1.0f + __expf(-rel_emb[rel * 64 + 2 * hl2 + 1]));
            gateg[idx] = make_float2(g0, g1);
        }
    }
    int n = e_kg + e_ui;
    int t = blockIdx.x * 256 + threadIdx.x;
    int stride = gridDim.x * 256;
    for (int e = t; e < n; e += stride) {
        int bk;
        if (e < e_kg) {
            int d = kg_dst[e];
            if (!getbit(ent_mask, d)) continue;
            bk = d >> 9;
        } else {
            int r = ui_row[e - e_kg];
            if (!getbit(node_mask, r)) continue;
            bk = NB_KG + (r >> 8);
        }
        atomicAdd(&h[bk], 1);
    }
    __syncthreads();
    for (int i = threadIdx.x; i < NB_TOT; i += 256)
        if (h[i]) atomicAdd(&bcnt[i], h[i]);
}

// ---------------------------------------------------------------------------
// Pass B: exclusive scan of bucket counts. boff[NB] = total KEPT edges.
// ---------------------------------------------------------------------------
__global__ __launch_bounds__(256) void bucket_scan(const int* __restrict__ bcnt,
                                                   int* __restrict__ boff_kg,
                                                   int* __restrict__ boff_ui,
                                                   int* __restrict__ bcur) {
    __shared__ int sh[1024];
    int t = threadIdx.x;
    for (int seg = 0; seg < 2; seg++) {
        int NB = seg ? NB_UI : NB_KG;
        const int* src = bcnt + (seg ? NB_KG : 0);
        int idx[4] = { t, t + 256, t + 512, t + 768 };
        int v[4];
        #pragma unroll
        for (int q = 0; q < 4; q++) {
            v[q] = (idx[q] < NB) ? src[idx[q]] : 0;
            sh[idx[q]] = v[q];
        }
        __syncthreads();
        for (int o = 1; o < 1024; o <<= 1) {
            int a[4];
            #pragma unroll
            for (int q = 0; q < 4; q++) a[q] = (idx[q] >= o) ? sh[idx[q] - o] : 0;
            __syncthreads();
            #pragma unroll
            for (int q = 0; q < 4; q++) sh[idx[q]] += a[q];
            __syncthreads();
        }
        int* boff = seg ? boff_ui : boff_kg;
        int  base = seg ? NB_KG : 0;
        #pragma unroll
        for (int q = 0; q < 4; q++) {
            if (idx[q] < NB) {
                int ex = sh[idx[q]] - v[q];
                boff[idx[q]] = ex;
                bcur[base + idx[q]] = ex;
                if (idx[q] == NB - 1) boff[NB] = sh[idx[q]];
            }
        }
        __syncthreads();
    }
}

// ---------------------------------------------------------------------------
// Pass C: scatter KEPT edges into bucket regions.
// CHUNK 4096 / 16 edges per thread — R5-proven config (R6's 1024-chunk split
// quadrupled the per-chunk atomic+scan overhead: 59 -> 81 us; reverted).
// Grid 768 so all 733 chunks run as one chunk per block.
// ---------------------------------------------------------------------------
__global__ __launch_bounds__(256) void bucket_scatter(const int* __restrict__ kg_src,
                                                      const int* __restrict__ kg_dst,
                                                      const int* __restrict__ kg_rel,
                                                      const int* __restrict__ ui_row,
                                                      const int* __restrict__ ui_col,
                                                      const float* __restrict__ ui_vals,
                                                      const unsigned* __restrict__ ent_mask,
                                                      const unsigned* __restrict__ node_mask,
                                                      int* __restrict__ bcur,
                                                      unsigned int* __restrict__ kgrec,
                                                      int* __restrict__ uirec,
                                                      float* __restrict__ uval,
                                                      int e_kg, int e_ui) {
    __shared__ int h[NB_TOT];
    __shared__ int lbase[NB_TOT];
    int n = e_kg + e_ui;
    int nchunks = (n + 4095) >> 12;
    int tid = threadIdx.x;
    for (int c = blockIdx.x; c < nchunks; c += gridDim.x) {
        int base = c << 12;
        for (int i = tid; i < NB_TOT; i += 256) h[i] = 0;
        __syncthreads();
        unsigned int rec[16];
        float val[16];
        int bk[16];
        #pragma unroll
        for (int j = 0; j < 16; j++) {
            int e = base + j * 256 + tid;
            bk[j] = -1;
            if (e < n) {
                if (e < e_kg) {
                    int d = kg_dst[e];
                    if (getbit(ent_mask, d)) {
                        bk[j]  = d >> 9;
                        rec[j] = (unsigned int)kg_src[e] | ((unsigned int)kg_rel[e] << 18)
                                 | ((unsigned int)(d & 511) << 23);
                        atomicAdd(&h[bk[j]], 1);
                    }
                } else {
                    int i2 = e - e_kg;
                    int r  = ui_row[i2];
                    if (getbit(node_mask, r)) {
                        bk[j]  = NB_KG + (r >> 8);
                        rec[j] = (unsigned int)ui_col[i2] | ((unsigned int)(r & 255) << 18);
                        val[j] = ui_vals[i2];
                        atomicAdd(&h[bk[j]], 1);
                    }
                }
            }
        }
        __syncthreads();
        for (int i = tid; i < NB_TOT; i += 256) {
            int cc = h[i];
            lbase[i] = cc ? atomicAdd(&bcur[i], cc) : 0;
        }
        __syncthreads();
        #pragma unroll
        for (int j = 0; j < 16; j++) {
            if (bk[j] >= 0) {
                int pos = atomicAdd(&lbase[bk[j]], 1);
                if (bk[j] < NB_KG) kgrec[pos] = rec[j];
                else               { uirec[pos] = (int)rec[j]; uval[pos] = val[j]; }
            }
        }
        __syncthreads();
    }
}

// ---------------------------------------------------------------------------
// Pass D: one block per bucket. LDS counting-sort of KEPT records.
// ---------------------------------------------------------------------------
__global__ __launch_bounds__(256) void bucket_finalize(const int* __restrict__ boff_kg,
                                                       const int* __restrict__ boff_ui,
                                                       unsigned int* __restrict__ kgrec,
                                                       int* __restrict__ uirec,
                                                       float* __restrict__ uval,
                                                       int* __restrict__ off_kg,
                                                       int* __restrict__ off_ui) {
    __shared__ unsigned int rec[CAPD];
    __shared__ float fval[CAPD];
    __shared__ int hist[512];
    bool iskg = blockIdx.x < NB_KG;
    int  b    = iskg ? blockIdx.x : blockIdx.x - NB_KG;
    const int* boff = iskg ? boff_kg : boff_ui;
    int ebeg = boff[b], eend = boff[b + 1];
    int ne   = min(eend - ebeg, CAPD);
    int key_base = iskg ? (b << 9) : (b << 8);
    int nkeys = iskg ? min(512, N_ENT - key_base) : min(256, N_NODES - key_base);
    int SH = iskg ? 23 : 18;
    int tid = threadIdx.x;

    for (int i = tid; i < ne; i += 256) {
        if (iskg) rec[i] = kgrec[ebeg + i];
        else { rec[i] = (unsigned int)uirec[ebeg + i]; fval[i] = uval[ebeg + i]; }
    }
    for (int i = tid; i < 512; i += 256) hist[i] = 0;
    __syncthreads();
    for (int i = tid; i < ne; i += 256)
        atomicAdd(&hist[rec[i] >> SH], 1);
    __syncthreads();
    int i0 = tid, i1 = tid + 256;
    int v0 = hist[i0], v1 = hist[i1];
    __syncthreads();
    for (int o = 1; o < 512; o <<= 1) {
        int a0 = (i0 >= o) ? hist[i0 - o] : 0;
        int a1 = (i1 >= o) ? hist[i1 - o] : 0;
        __syncthreads();
        hist[i0] += a0; hist[i1] += a1;
        __syncthreads();
    }
    int e0 = hist[i0] - v0, e1 = hist[i1] - v1;
    __syncthreads();
    hist[i0] = e0; hist[i1] = e1;
    int* offg = iskg ? off_kg : off_ui;
    if (i0 < nkeys) offg[key_base + i0] = ebeg + e0;
    if (i1 < nkeys) offg[key_base + i1] = ebeg + e1;
    if (blockIdx.x == 0 && tid == 0) {
        off_kg[N_ENT]   = boff_kg[NB_KG];
        off_ui[N_NODES] = boff_ui[NB_UI];
    }
    __syncthreads();
    for (int i = tid; i < ne; i += 256) {
        unsigned int r = rec[i];
        int k = r >> SH;
        int slot = atomicAdd(&hist[k], 1);
        if (iskg) kgrec[ebeg + slot] = r & 0x7FFFFFu;
        else      { uirec[ebeg + slot] = (int)(r & 0x3FFFFu); uval[ebeg + slot] = fval[i]; }
    }
}

// ---------------------------------------------------------------------------
// kgagg_build: TWO NODES PER WAVE, one per half-wave (32 lanes).
// Half layout: 16 lanes x uint2 per row (dims 4ql..4ql+3), 2 edge slots.
// ---------------------------------------------------------------------------
__global__ __launch_bounds__(256) void kgagg_build(const int* __restrict__ off,
                                                   const unsigned int* __restrict__ packed,
                                                   const unsigned short* __restrict__ y16,
                                                   const float* __restrict__ entity_emb,
                                                   const float* __restrict__ user_emb,
                                                   const int* __restrict__ i2e,
                                                   const float4* __restrict__ gate4,
                                                   float* __restrict__ all_emb,
                                                   unsigned short* __restrict__ all16) {
    int lane = threadIdx.x & 63;
    int half = lane >> 5;          // which node of the pair
    int hl   = lane & 31;
    int duo  = hl >> 4;            // edge slot within half
    int ql   = hl & 15;            // dims 4ql..4ql+3
    long wpair = (long)((blockIdx.x * 256 + threadIdx.x) >> 6);
    int w = (int)(wpair * 2 + half);
    if (w >= N_NODES) return;      // N_NODES even: whole wave exits together

    if (w < N_USERS) {             // both halves users: bf16 copy only
        if (duo == 0) {
            float4 v = ((const float4*)user_emb)[(long)w * 16 + ql];
            ((uint2*)all16)[(long)w * 16 + ql] =
                make_uint2((unsigned)f2bf(v.x) | ((unsigned)f2bf(v.y) << 16),
                           (unsigned)f2bf(v.z) | ((unsigned)f2bf(v.w) << 16));
        }
        return;
    }

    int ent = i2e[w - N_USERS];    // half-uniform (broadcast load)
    const uint2* y2 = (const uint2*)y16;
    int beg = off[ent], end = off[ent + 1];
    float a0 = 0.f, a1 = 0.f, a2 = 0.f, a3 = 0.f;
    float b0 = 0.f, b1 = 0.f, b2 = 0.f, b3 = 0.f;
    int p = beg;
    for (; p + 4 <= end; p += 4) {     // 4 edges per half per iter
        unsigned pk0 = packed[p + duo];
        unsigned pk1 = packed[p + 2 + duo];
        uint2 v0 = y2[(long)(pk0 & 0x3FFFF) * 16 + ql];
        uint2 v1 = y2[(long)(pk1 & 0x3FFFF) * 16 + ql];
        float4 g0 = gate4[(pk0 >> 18) * 16 + ql];
        float4 g1 = gate4[(pk1 >> 18) * 16 + ql];
        a0 += bf_lo(v0.x) * g0.x;  a1 += bf_hi(v0.x) * g0.y;
        a2 += bf_lo(v0.y) * g0.z;  a3 += bf_hi(v0.y) * g0.w;
        b0 += bf_lo(v1.x) * g1.x;  b1 += bf_hi(v1.x) * g1.y;
        b2 += bf_lo(v1.y) * g1.z;  b3 += bf_hi(v1.y) * g1.w;
    }
    if (p + duo < end) {               // tail edges p..p+1
        unsigned pk = packed[p + duo];
        uint2 v = y2[(long)(pk & 0x3FFFF) * 16 + ql];
        float4 g = gate4[(pk >> 18) * 16 + ql];
        a0 += bf_lo(v.x) * g.x;  a1 += bf_hi(v.x) * g.y;
        a2 += bf_lo(v.y) * g.z;  a3 += bf_hi(v.y) * g.w;
    }
    if (p + 2 + duo < end) {           // tail edge p+2 (p+3 impossible)
        unsigned pk = packed[p + 2 + duo];
        uint2 v = y2[(long)(pk & 0x3FFFF) * 16 + ql];
        float4 g = gate4[(pk >> 18) * 16 + ql];
        b0 += bf_lo(v.x) * g.x;  b1 += bf_hi(v.x) * g.y;
        b2 += bf_lo(v.y) * g.z;  b3 += bf_hi(v.y) * g.w;
    }
    a0 += b0; a1 += b1; a2 += b2; a3 += b3;
    a0 += __shfl_xor(a0, 16);          // merge the two duo slots (within half)
    a1 += __shfl_xor(a1, 16);
    a2 += __shfl_xor(a2, 16);
    a3 += __shfl_xor(a3, 16);

    float deg = fmaxf((float)(end - beg), 1.0f);
    float4 xv = ((const float4*)entity_emb)[(long)ent * 16 + ql];
    float v0 = a0 / deg + xv.x;
    float v1 = a1 / deg + xv.y;
    float v2 = a2 / deg + xv.z;
    float v3 = a3 / deg + xv.w;
    v0 = (v0 > 0.0f) ? v0 : (__expf(v0) - 1.0f);
    v1 = (v1 > 0.0f) ? v1 : (__expf(v1) - 1.0f);
    v2 = (v2 > 0.0f) ? v2 : (__expf(v2) - 1.0f);
    v3 = (v3 > 0.0f) ? v3 : (__expf(v3) - 1.0f);
    float ss = v0 * v0 + v1 * v1 + v2 * v2 + v3 * v3;
    ss += __shfl_xor(ss, 1);
    ss += __shfl_xor(ss, 2);
    ss += __shfl_xor(ss, 4);
    ss += __shfl_xor(ss, 8);
    float inv = 1.0f / fmaxf(sqrtf(ss), 1e-12f);
    if (duo == 0) {
        float r0 = v0 * inv, r1 = v1 * inv, r2 = v2 * inv, r3 = v3 * inv;
        ((float4*)all_emb)[(long)w * 16 + ql] = make_float4(r0, r1, r2, r3);
        ((uint2*)all16)[(long)w * 16 + ql] =
            make_uint2((unsigned)f2bf(r0) | ((unsigned)f2bf(r1) << 16),
                       (unsigned)f2bf(r2) | ((unsigned)f2bf(r3) << 16));
    }
}

// ---------------------------------------------------------------------------
// ui_aggregate_s: TWO SAMPLE ROWS PER WAVE (same half-wave transform).
// ---------------------------------------------------------------------------
__global__ __launch_bounds__(256) void ui_aggregate_s(const int* __restrict__ off,
                                                      const int* __restrict__ colrec,
                                                      const float* __restrict__ uval,
                                                      const float* __restrict__ all_emb,
                                                      const float* __restrict__ user_emb,
                                                      const unsigned short* __restrict__ all16,
                                                      const int* __restrict__ u,
                                                      const int* __restrict__ ipos,
                                                      const int* __restrict__ ineg,
                                                      float* __restrict__ final_emb, int B) {
    const uint2* a2p = (const uint2*)all16;
    int lane = threadIdx.x & 63;
    int half = lane >> 5;
    int hl   = lane & 31;
    int duo  = hl >> 4;
    int ql   = hl & 15;
    long wpair = (long)((blockIdx.x * 256 + threadIdx.x) >> 6);
    int s = (int)(wpair * 2 + half);
    if (s >= 3 * B) return;            // 3B even: whole wave exits together
    int r;
    if (s < B)          r = u[s];
    else if (s < 2 * B) r = N_USERS + ipos[s - B];
    else                r = N_USERS + ineg[s - 2 * B];

    int beg = off[r], end = off[r + 1];
    float a0 = 0.f, a1 = 0.f, a2 = 0.f, a3 = 0.f;
    float b0 = 0.f, b1 = 0.f, b2 = 0.f, b3 = 0.f;
    int p = beg;
    for (; p + 4 <= end; p += 4) {
        int   c0 = colrec[p + duo];
        int   c1 = colrec[p + 2 + duo];
        float d0 = uval[p + duo];
        float d1 = uval[p + 2 + duo];
        uint2 v0 = a2p[(long)c0 * 16 + ql];
        uint2 v1 = a2p[(long)c1 * 16 + ql];
        a0 += d0 * bf_lo(v0.x);  a1 += d0 * bf_hi(v0.x);
        a2 += d0 * bf_lo(v0.y);  a3 += d0 * bf_hi(v0.y);
        b0 += d1 * bf_lo(v1.x);  b1 += d1 * bf_hi(v1.x);
        b2 += d1 * bf_lo(v1.y);  b3 += d1 * bf_hi(v1.y);
    }
    if (p + duo < end) {
        int   c = colrec[p + duo];
        float d = uval[p + duo];
        uint2 v = a2p[(long)c * 16 + ql];
        a0 += d * bf_lo(v.x);  a1 += d * bf_hi(v.x);
        a2 += d * bf_lo(v.y);  a3 += d * bf_hi(v.y);
    }
    if (p + 2 + duo < end) {
        int   c = colrec[p + 2 + duo];
        float d = uval[p + 2 + duo];
        uint2 v = a2p[(long)c * 16 + ql];
        b0 += d * bf_lo(v.x);  b1 += d * bf_hi(v.x);
        b2 += d * bf_lo(v.y);  b3 += d * bf_hi(v.y);
    }
    a0 += b0; a1 += b1; a2 += b2; a3 += b3;
    a0 += __shfl_xor(a0, 16);
    a1 += __shfl_xor(a1, 16);
    a2 += __shfl_xor(a2, 16);
    a3 += __shfl_xor(a3, 16);
    if (duo == 0) {
        float4 ae = (r < N_USERS)
            ? ((const float4*)user_emb)[(long)r * 16 + ql]
            : ((const float4*)all_emb)[(long)r * 16 + ql];
        ((float4*)final_emb)[(long)r * 16 + ql] =
            make_float4(0.5f * (ae.x + a0), 0.5f * (ae.y + a1),
                        0.5f * (ae.z + a2), 0.5f * (ae.w + a3));
    }
}

// ---------------------------------------------------------------------------
// Epilogue (intent folded in): one wave per sample.
// ---------------------------------------------------------------------------
__global__ void final_kernel(const int* __restrict__ u, const int* __restrict__ ipos,
                             const int* __restrict__ ineg,
                             const float* __restrict__ final_emb,
                             const float* __restrict__ all_emb,
                             const float* __restrict__ rw, const float* __restrict__ rb,
                             const float* __restrict__ iw, const float* __restrict__ rel_emb,
                             float* __restrict__ out, int B) {
    __shared__ float sh_intent[128];
    if (threadIdx.x < 64) {
        int j = threadIdx.x;
        for (int k = 0; k < 2; k++) {
            float m = -1e30f;
            for (int r = 0; r < N_REL; r++) m = fmaxf(m, iw[k * N_REL + r]);
            float Z = 0.f, acc = 0.f;
            for (int r = 0; r < N_REL; r++) {
                float e = __expf(iw[k * N_REL + r] - m);
                Z += e;
                acc += e * rel_emb[r * 64 + j];
            }
            sh_intent[k * 64 + j] = acc / Z;
        }
    }
    __syncthreads();
    int lane = threadIdx.x & 63;
    int wave = (blockIdx.x * blockDim.x + threadIdx.x) >> 6;
    int nw   = (gridDim.x * blockDim.x) >> 6;
    for (int b = wave; b < B; b += nw) {
        int uu = u[b];
        float up = final_emb[(long)uu * 64 + lane];
        float l0 = up * rw[lane];
        float l1 = up * rw[64 + lane];
        #pragma unroll
        for (int o = 32; o; o >>= 1) {
            l0 += __shfl_xor(l0, o);
            l1 += __shfl_xor(l1, o);
        }
        l0 += rb[0]; l1 += rb[1];
        float m  = fmaxf(l0, l1);
        float e0 = __expf(l0 - m), e1 = __expf(l1 - m);
        float inv = 1.0f / (e0 + e1);
        float p0 = e0 * inv, p1 = e1 * inv;
        float ue = up + p0 * sh_intent[lane] + p1 * sh_intent[64 + lane];

        int it = ipos[b];
        long rr = (long)(N_USERS + it) * 64 + lane;
        float ie = final_emb[rr] + all_emb[rr];
        float dp = ue * ie;
        #pragma unroll
        for (int o = 32; o; o >>= 1) dp += __shfl_xor(dp, o);
        if (lane == 0) out[b] = dp;

        it = ineg[b];
        rr = (long)(N_USERS + it) * 64 + lane;
        ie = final_emb[rr] + all_emb[rr];
        dp = ue * ie;
        #pragma unroll
        for (int o = 32; o; o >>= 1) dp += __shfl_xor(dp, o);
        if (lane == 0) out[B + b] = dp;
    }
}

extern "C" void kernel_launch(void* const* d_in, const int* in_sizes, int n_in,
                              void* d_out, int out_size, void* d_ws, size_t ws_size,
                              hipStream_t stream) {
    const int*   u          = (const int*)  d_in[0];
    const int*   ipos       = (const int*)  d_in[1];
    const int*   ineg       = (const int*)  d_in[2];
    const float* user_emb   = (const float*)d_in[3];
    const float* entity_emb = (const float*)d_in[4];
    const float* rel_emb    = (const float*)d_in[5];
    const float* iw         = (const float*)d_in[6];
    const float* rw         = (const float*)d_in[7];
    const float* rb         = (const float*)d_in[8];
    const float* kgw        = (const float*)d_in[9];
    const float* ui_vals    = (const float*)d_in[10];
    const int*   i2e        = (const int*)  d_in[11];
    const int*   kg_src     = (const int*)  d_in[12];
    const int*   kg_dst     = (const int*)  d_in[13];
    const int*   kg_rel     = (const int*)  d_in[14];
    const int*   ui_row     = (const int*)  d_in[15];
    const int*   ui_col     = (const int*)  d_in[16];
    float*       out        = (float*)d_out;

    int B    = in_sizes[0];
    int e_kg = in_sizes[12];
    int e_ui = in_sizes[15];

    // ---------------- workspace layout (bytes) ----------------
    char* ws = (char*)d_ws;
    unsigned short* y16       = (unsigned short*)(ws + 0);        // 25.6 MB
    float*          all_emb   = (float*)(ws + 25600000);          // 38.4 MB
    unsigned short* all16     = (unsigned short*)(ws + 64000000); // 19.2 MB
    float*          final_emb = (float*)(ws + 83200000);          // 38.4 MB (sparse use)
    unsigned int*   kgrec     = (unsigned int*)(ws + 121600000);  // 8 MB
    int*            uirec     = (int*)(ws + 129600000);           // 4 MB
    float*          uval      = (float*)(ws + 133600000);         // 4 MB
    int*            off_kg    = (int*)(ws + 137600000);           // 200001 ints
    int*            off_ui    = (int*)(ws + 138400256);           // 150001 ints
    unsigned*       ent_mask  = (unsigned*)(ws + 139000512);      // 25088 B (200K bits)
    unsigned*       node_mask = (unsigned*)(ws + 139025600);      // 18752 B (150K bits)
    int*            bcnt      = (int*)(ws + 139600512);           // 977 ints
    int*            boff_kg   = (int*)(ws + 139604480);           // 392 ints
    int*            boff_ui   = (int*)(ws + 139606272);           // 587 ints
    int*            bcur      = (int*)(ws + 139608704);           // 977 ints
    float2*         gateg     = (float2*)(ws + 139612672);        // 8 KB gate table

    hipMemsetAsync(ent_mask, 0, 25088 + 18752, stream);   // masks contiguous
    build_masks    <<<512, 256, 0, stream>>>(i2e, u, ipos, ineg, ent_mask, node_mask,
                                             bcnt, B);
    bucket_hist    <<<1024, 256, 0, stream>>>(kg_dst, ui_row, ent_mask, node_mask,
                                              rel_emb, gateg, bcnt, e_kg, e_ui);
    bucket_scan    <<<1,   256, 0, stream>>>(bcnt, boff_kg, boff_ui, bcur);
    bucket_scatter <<<768, 256, 0, stream>>>(kg_src, kg_dst, kg_rel, ui_row, ui_col,
                                             ui_vals, ent_mask, node_mask,
                                             bcur, kgrec, uirec, uval, e_kg, e_ui);
    bucket_finalize<<<NB_TOT, 256, 0, stream>>>(boff_kg, boff_ui, kgrec, uirec, uval,
                                                off_kg, off_ui);

    ent_matmul <<<(N_ENT + 127) / 128, 128, 0, stream>>>(entity_emb, kgw, y16, N_ENT);
    {   // two nodes per wave
        int nwaves = (N_NODES + 1) / 2;
        int nblk   = (nwaves * 64 + 255) / 256;
        kgagg_build<<<nblk, 256, 0, stream>>>(
            off_kg, kgrec, y16, entity_emb, user_emb, i2e, (const float4*)gateg,
            all_emb, all16);
    }
    {   // two sample rows per wave
        int nwaves = (3 * B + 1) / 2;
        int nblk   = (nwaves * 64 + 255) / 256;
        ui_aggregate_s<<<nblk, 256, 0, stream>>>(
            off_ui, uirec, uval, all_emb, user_emb, all16, u, ipos, ineg, final_emb, B);
    }
    final_kernel<<<256, 256, 0, stream>>>(u, ipos, ineg, final_emb, all_emb,
                                          rw, rb, iw, rel_emb, out, B);
}

// Round 8
// 330.519 us; speedup vs baseline: 1.2165x; 1.0896x over previous
//
#include <hip/hip_runtime.h>
#include <math.h>

#define N_USERS 50000
#define N_ITEMS 100000
#define N_ENT   200000
#define N_NODES (N_USERS + N_ITEMS)
#define N_REL   32
#define DIM     64

#define NB_KG  391          // KG buckets: dst>>9 (512 keys each)
#define NB_UI  586          // UI buckets: row>>8 (256 keys each)
#define NB_TOT (NB_KG + NB_UI)   // 977
#define CAPD   4096         // max KEPT edges per bucket (post-filter)

__device__ __forceinline__ unsigned short f2bf(float f) {   // RNE f32->bf16
    unsigned u = __float_as_uint(f);
    u += 0x7FFFu + ((u >> 16) & 1u);
    return (unsigned short)(u >> 16);
}
__device__ __forceinline__ float bf_lo(unsigned v) { return __uint_as_float(v << 16); }
__device__ __forceinline__ float bf_hi(unsigned v) { return __uint_as_float(v & 0xFFFF0000u); }
__device__ __forceinline__ int getbit(const unsigned* m, int i) {
    return (m[i >> 5] >> (i & 31)) & 1;
}

// ---------------------------------------------------------------------------
// ent_matmul: y16 = bf16(x @ W^T), swizzled-LDS GEMM, 256 threads/block.
// R7 evidence: swizzle killed conflicts (4.2M->600K) but dur stayed 59us at
// 12% occupancy (2 waves/block x 3 blocks/CU = 1.5 waves/SIMD — latency
// starved). Same 128-row tile + 48KB LDS, but 4 waves/block -> 12 waves/CU.
// Each thread now computes 4x8 (was 8x8). Per-output FMA order is k-ascending
// with identical operands -> BIT-IDENTICAL numerics.
// ---------------------------------------------------------------------------
__global__ __launch_bounds__(256) void ent_matmul(const float* __restrict__ x,
                                                  const float* __restrict__ w,
                                                  unsigned short* __restrict__ y16,
                                                  int n_ent) {
    __shared__ float xt[64][128];
    __shared__ float wt[64][64];
    int tid  = threadIdx.x;
    int base = blockIdx.x * 128;

    #pragma unroll
    for (int q = 0; q < 4; q++) {
        int idx = q * 256 + tid;          // 1024 float4 of w
        int j = idx >> 4, k4 = idx & 15;
        int s0 = (k4 << 2) & 28;          // sigma for rows 4k4..4k4+3
        float4 v = ((const float4*)w)[idx];
        wt[4 * k4 + 0][j ^ s0] = v.x;
        wt[4 * k4 + 1][j ^ s0] = v.y;
        wt[4 * k4 + 2][j ^ s0] = v.z;
        wt[4 * k4 + 3][j ^ s0] = v.w;
    }
    #pragma unroll
    for (int q = 0; q < 8; q++) {
        int idx = q * 256 + tid;          // 2048 float4 of x
        int r = idx >> 4, k4 = idx & 15;
        int gr = base + r;
        int s0 = (k4 << 2) & 28;
        if (gr < n_ent) {
            float4 v = ((const float4*)x)[(long)gr * 16 + k4];
            xt[4 * k4 + 0][r ^ s0] = v.x;
            xt[4 * k4 + 1][r ^ s0] = v.y;
            xt[4 * k4 + 2][r ^ s0] = v.z;
            xt[4 * k4 + 3][r ^ s0] = v.w;
        }
    }
    __syncthreads();

    int j0 = (tid & 7) * 8;               // 8 output cols
    int r0 = (tid >> 3) * 4;              // 4 output rows (0..124)
    float acc[4][8];
    #pragma unroll
    for (int i = 0; i < 4; i++)
        #pragma unroll
        for (int j = 0; j < 8; j++) acc[i][j] = 0.f;

    #pragma unroll 4
    for (int k = 0; k < 64; k++) {
        int s = k & 28;
        float4 xa = *(const float4*)&xt[k][r0 ^ s];
        float4 wa = *(const float4*)&wt[k][j0 ^ s];
        float4 wb = *(const float4*)&wt[k][(j0 + 4) ^ s];
        float xr[4] = {xa.x, xa.y, xa.z, xa.w};
        float wr[8] = {wa.x, wa.y, wa.z, wa.w, wb.x, wb.y, wb.z, wb.w};
        #pragma unroll
        for (int i = 0; i < 4; i++)
            #pragma unroll
            for (int j = 0; j < 8; j++)
                acc[i][j] += xr[i] * wr[j];
    }

    #pragma unroll
    for (int i = 0; i < 4; i++) {
        int gr = base + r0 + i;
        if (gr < n_ent) {
            uint4 o;
            o.x = (unsigned)f2bf(acc[i][0]) | ((unsigned)f2bf(acc[i][1]) << 16);
            o.y = (unsigned)f2bf(acc[i][2]) | ((unsigned)f2bf(acc[i][3]) << 16);
            o.z = (unsigned)f2bf(acc[i][4]) | ((unsigned)f2bf(acc[i][5]) << 16);
            o.w = (unsigned)f2bf(acc[i][6]) | ((unsigned)f2bf(acc[i][7]) << 16);
            *(uint4*)&y16[(long)gr * 64 + j0] = o;
        }
    }
}

// ---------------------------------------------------------------------------
// build_masks: membership bitmaps + zero bcnt.
// ---------------------------------------------------------------------------
__global__ __launch_bounds__(256) void build_masks(const int* __restrict__ i2e,
                                                   const int* __restrict__ u,
                                                   const int* __restrict__ ipos,
                                                   const int* __restrict__ ineg,
                                                   unsigned* __restrict__ ent_mask,
                                                   unsigned* __restrict__ node_mask,
                                                   int* __restrict__ bcnt,
                                                   int B) {
    int t = blockIdx.x * 256 + threadIdx.x;
    int stride = gridDim.x * 256;
    for (int i = threadIdx.x; i < NB_TOT; i += 256) bcnt[i] = 0;
    for (int i = t; i < N_ITEMS; i += stride) {
        int e = i2e[i];
        atomicOr(&ent_mask[e >> 5], 1u << (e & 31));
    }
    for (int i = t; i < 3 * B; i += stride) {
        int r = (i < B) ? u[i]
              : (i < 2 * B) ? N_USERS + ipos[i - B]
                            : N_USERS + ineg[i - 2 * B];
        atomicOr(&node_mask[r >> 5], 1u << (r & 31));
    }
}

// ---------------------------------------------------------------------------
// Pass A: per-block LDS bucket histogram over KEPT edges only.
// Block 0 additionally precomputes the sigmoid gate table ONCE into gateg.
// ---------------------------------------------------------------------------
__global__ __launch_bounds__(256) void bucket_hist(const int* __restrict__ kg_dst,
                                                   const int* __restrict__ ui_row,
                                                   const unsigned* __restrict__ ent_mask,
                                                   const unsigned* __restrict__ node_mask,
                                                   const float* __restrict__ rel_emb,
                                                   float2* __restrict__ gateg,
                                                   int* __restrict__ bcnt,
                                                   int e_kg, int e_ui) {
    __shared__ int h[NB_TOT];
    for (int i = threadIdx.x; i < NB_TOT; i += 256) h[i] = 0;
    __syncthreads();
    if (blockIdx.x == 0) {
        for (int idx = threadIdx.x; idx < N_REL * 32; idx += 256) {
            int rel = idx >> 5, hl2 = idx & 31;
            float g0 = 1.0f / (1.0f + __expf(-rel_emb[rel * 64 + 2 * hl2]));
            float g1 = 1.0f / (1.0f + __expf(-rel_emb[rel * 64 + 2 * hl2 + 1]));
            gateg[idx] = make_float2(g0, g1);
        }
    }
    int n = e_kg + e_ui;
    int t = blockIdx.x * 256 + threadIdx.x;
    int stride = gridDim.x * 256;
    for (int e = t; e < n; e += stride) {
        int bk;
        if (e < e_kg) {
            int d = kg_dst[e];
            if (!getbit(ent_mask, d)) continue;
            bk = d >> 9;
        } else {
            int r = ui_row[e - e_kg];
            if (!getbit(node_mask, r)) continue;
            bk = NB_KG + (r >> 8);
        }
        atomicAdd(&h[bk], 1);
    }
    __syncthreads();
    for (int i = threadIdx.x; i < NB_TOT; i += 256)
        if (h[i]) atomicAdd(&bcnt[i], h[i]);
}

// ---------------------------------------------------------------------------
// Pass B: exclusive scan of bucket counts. boff[NB] = total KEPT edges.
// ---------------------------------------------------------------------------
__global__ __launch_bounds__(256) void bucket_scan(const int* __restrict__ bcnt,
                                                   int* __restrict__ boff_kg,
                                                   int* __restrict__ boff_ui,
                                                   int* __restrict__ bcur) {
    __shared__ int sh[1024];
    int t = threadIdx.x;
    for (int seg = 0; seg < 2; seg++) {
        int NB = seg ? NB_UI : NB_KG;
        const int* src = bcnt + (seg ? NB_KG : 0);
        int idx[4] = { t, t + 256, t + 512, t + 768 };
        int v[4];
        #pragma unroll
        for (int q = 0; q < 4; q++) {
            v[q] = (idx[q] < NB) ? src[idx[q]] : 0;
            sh[idx[q]] = v[q];
        }
        __syncthreads();
        for (int o = 1; o < 1024; o <<= 1) {
            int a[4];
            #pragma unroll
            for (int q = 0; q < 4; q++) a[q] = (idx[q] >= o) ? sh[idx[q] - o] : 0;
            __syncthreads();
            #pragma unroll
            for (int q = 0; q < 4; q++) sh[idx[q]] += a[q];
            __syncthreads();
        }
        int* boff = seg ? boff_ui : boff_kg;
        int  base = seg ? NB_KG : 0;
        #pragma unroll
        for (int q = 0; q < 4; q++) {
            if (idx[q] < NB) {
                int ex = sh[idx[q]] - v[q];
                boff[idx[q]] = ex;
                bcur[base + idx[q]] = ex;
                if (idx[q] == NB - 1) boff[NB] = sh[idx[q]];
            }
        }
        __syncthreads();
    }
}

// ---------------------------------------------------------------------------
// Pass C: scatter KEPT edges into bucket regions.
// CHUNK 4096 (proven), but 512 threads x 8 edges: per-thread arrays fit in
// VGPRs (R7's 16-edge form showed VGPR_Count=32 -> rec/val/bk in scratch),
// and each chunk's phases get 8 waves of latency cover.
// ---------------------------------------------------------------------------
__global__ __launch_bounds__(512) void bucket_scatter(const int* __restrict__ kg_src,
                                                      const int* __restrict__ kg_dst,
                                                      const int* __restrict__ kg_rel,
                                                      const int* __restrict__ ui_row,
                                                      const int* __restrict__ ui_col,
                                                      const float* __restrict__ ui_vals,
                                                      const unsigned* __restrict__ ent_mask,
                                                      const unsigned* __restrict__ node_mask,
                                                      int* __restrict__ bcur,
                                                      unsigned int* __restrict__ kgrec,
                                                      int* __restrict__ uirec,
                                                      float* __restrict__ uval,
                                                      int e_kg, int e_ui) {
    __shared__ int h[NB_TOT];
    __shared__ int lbase[NB_TOT];
    int n = e_kg + e_ui;
    int nchunks = (n + 4095) >> 12;
    int tid = threadIdx.x;
    for (int c = blockIdx.x; c < nchunks; c += gridDim.x) {
        int base = c << 12;
        for (int i = tid; i < NB_TOT; i += 512) h[i] = 0;
        __syncthreads();
        unsigned int rec[8];
        float val[8];
        int bk[8];
        #pragma unroll
        for (int j = 0; j < 8; j++) {
            int e = base + j * 512 + tid;
            bk[j] = -1;
            if (e < n) {
                if (e < e_kg) {
                    int d = kg_dst[e];
                    if (getbit(ent_mask, d)) {
                        bk[j]  = d >> 9;
                        rec[j] = (unsigned int)kg_src[e] | ((unsigned int)kg_rel[e] << 18)
                                 | ((unsigned int)(d & 511) << 23);
                        atomicAdd(&h[bk[j]], 1);
                    }
                } else {
                    int i2 = e - e_kg;
                    int r  = ui_row[i2];
                    if (getbit(node_mask, r)) {
                        bk[j]  = NB_KG + (r >> 8);
                        rec[j] = (unsigned int)ui_col[i2] | ((unsigned int)(r & 255) << 18);
                        val[j] = ui_vals[i2];
                        atomicAdd(&h[bk[j]], 1);
                    }
                }
            }
        }
        __syncthreads();
        for (int i = tid; i < NB_TOT; i += 512) {
            int cc = h[i];
            lbase[i] = cc ? atomicAdd(&bcur[i], cc) : 0;
        }
        __syncthreads();
        #pragma unroll
        for (int j = 0; j < 8; j++) {
            if (bk[j] >= 0) {
                int pos = atomicAdd(&lbase[bk[j]], 1);
                if (bk[j] < NB_KG) kgrec[pos] = rec[j];
                else               { uirec[pos] = (int)rec[j]; uval[pos] = val[j]; }
            }
        }
        __syncthreads();
    }
}

// ---------------------------------------------------------------------------
// Pass D: one block per bucket. LDS counting-sort of KEPT records.
// ---------------------------------------------------------------------------
__global__ __launch_bounds__(256) void bucket_finalize(const int* __restrict__ boff_kg,
                                                       const int* __restrict__ boff_ui,
                                                       unsigned int* __restrict__ kgrec,
                                                       int* __restrict__ uirec,
                                                       float* __restrict__ uval,
                                                       int* __restrict__ off_kg,
                                                       int* __restrict__ off_ui) {
    __shared__ unsigned int rec[CAPD];
    __shared__ float fval[CAPD];
    __shared__ int hist[512];
    bool iskg = blockIdx.x < NB_KG;
    int  b    = iskg ? blockIdx.x : blockIdx.x - NB_KG;
    const int* boff = iskg ? boff_kg : boff_ui;
    int ebeg = boff[b], eend = boff[b + 1];
    int ne   = min(eend - ebeg, CAPD);
    int key_base = iskg ? (b << 9) : (b << 8);
    int nkeys = iskg ? min(512, N_ENT - key_base) : min(256, N_NODES - key_base);
    int SH = iskg ? 23 : 18;
    int tid = threadIdx.x;

    for (int i = tid; i < ne; i += 256) {
        if (iskg) rec[i] = kgrec[ebeg + i];
        else { rec[i] = (unsigned int)uirec[ebeg + i]; fval[i] = uval[ebeg + i]; }
    }
    for (int i = tid; i < 512; i += 256) hist[i] = 0;
    __syncthreads();
    for (int i = tid; i < ne; i += 256)
        atomicAdd(&hist[rec[i] >> SH], 1);
    __syncthreads();
    int i0 = tid, i1 = tid + 256;
    int v0 = hist[i0], v1 = hist[i1];
    __syncthreads();
    for (int o = 1; o < 512; o <<= 1) {
        int a0 = (i0 >= o) ? hist[i0 - o] : 0;
        int a1 = (i1 >= o) ? hist[i1 - o] : 0;
        __syncthreads();
        hist[i0] += a0; hist[i1] += a1;
        __syncthreads();
    }
    int e0 = hist[i0] - v0, e1 = hist[i1] - v1;
    __syncthreads();
    hist[i0] = e0; hist[i1] = e1;
    int* offg = iskg ? off_kg : off_ui;
    if (i0 < nkeys) offg[key_base + i0] = ebeg + e0;
    if (i1 < nkeys) offg[key_base + i1] = ebeg + e1;
    if (blockIdx.x == 0 && tid == 0) {
        off_kg[N_ENT]   = boff_kg[NB_KG];
        off_ui[N_NODES] = boff_ui[NB_UI];
    }
    __syncthreads();
    for (int i = tid; i < ne; i += 256) {
        unsigned int r = rec[i];
        int k = r >> SH;
        int slot = atomicAdd(&hist[k], 1);
        if (iskg) kgrec[ebeg + slot] = r & 0x7FFFFFu;
        else      { uirec[ebeg + slot] = (int)(r & 0x3FFFFu); uval[ebeg + slot] = fval[i]; }
    }
}

// ---------------------------------------------------------------------------
// kgagg_build: TWO NODES PER WAVE, one per half-wave (32 lanes).
// Half layout: 16 lanes x uint2 per row (dims 4ql..4ql+3), 2 edge slots.
// ---------------------------------------------------------------------------
__global__ __launch_bounds__(256) void kgagg_build(const int* __restrict__ off,
                                                   const unsigned int* __restrict__ packed,
                                                   const unsigned short* __restrict__ y16,
                                                   const float* __restrict__ entity_emb,
                                                   const float* __restrict__ user_emb,
                                                   const int* __restrict__ i2e,
                                                   const float4* __restrict__ gate4,
                                                   float* __restrict__ all_emb,
                                                   unsigned short* __restrict__ all16) {
    int lane = threadIdx.x & 63;
    int half = lane >> 5;          // which node of the pair
    int hl   = lane & 31;
    int duo  = hl >> 4;            // edge slot within half
    int ql   = hl & 15;            // dims 4ql..4ql+3
    long wpair = (long)((blockIdx.x * 256 + threadIdx.x) >> 6);
    int w = (int)(wpair * 2 + half);
    if (w >= N_NODES) return;      // N_NODES even: whole wave exits together

    if (w < N_USERS) {             // both halves users: bf16 copy only
        if (duo == 0) {
            float4 v = ((const float4*)user_emb)[(long)w * 16 + ql];
            ((uint2*)all16)[(long)w * 16 + ql] =
                make_uint2((unsigned)f2bf(v.x) | ((unsigned)f2bf(v.y) << 16),
                           (unsigned)f2bf(v.z) | ((unsigned)f2bf(v.w) << 16));
        }
        return;
    }

    int ent = i2e[w - N_USERS];    // half-uniform (broadcast load)
    const uint2* y2 = (const uint2*)y16;
    int beg = off[ent], end = off[ent + 1];
    float a0 = 0.f, a1 = 0.f, a2 = 0.f, a3 = 0.f;
    float b0 = 0.f, b1 = 0.f, b2 = 0.f, b3 = 0.f;
    int p = beg;
    for (; p + 4 <= end; p += 4) {     // 4 edges per half per iter
        unsigned pk0 = packed[p + duo];
        unsigned pk1 = packed[p + 2 + duo];
        uint2 v0 = y2[(long)(pk0 & 0x3FFFF) * 16 + ql];
        uint2 v1 = y2[(long)(pk1 & 0x3FFFF) * 16 + ql];
        float4 g0 = gate4[(pk0 >> 18) * 16 + ql];
        float4 g1 = gate4[(pk1 >> 18) * 16 + ql];
        a0 += bf_lo(v0.x) * g0.x;  a1 += bf_hi(v0.x) * g0.y;
        a2 += bf_lo(v0.y) * g0.z;  a3 += bf_hi(v0.y) * g0.w;
        b0 += bf_lo(v1.x) * g1.x;  b1 += bf_hi(v1.x) * g1.y;
        b2 += bf_lo(v1.y) * g1.z;  b3 += bf_hi(v1.y) * g1.w;
    }
    if (p + duo < end) {               // tail edges p..p+1
        unsigned pk = packed[p + duo];
        uint2 v = y2[(long)(pk & 0x3FFFF) * 16 + ql];
        float4 g = gate4[(pk >> 18) * 16 + ql];
        a0 += bf_lo(v.x) * g.x;  a1 += bf_hi(v.x) * g.y;
        a2 += bf_lo(v.y) * g.z;  a3 += bf_hi(v.y) * g.w;
    }
    if (p + 2 + duo < end) {           // tail edge p+2 (p+3 impossible)
        unsigned pk = packed[p + 2 + duo];
        uint2 v = y2[(long)(pk & 0x3FFFF) * 16 + ql];
        float4 g = gate4[(pk >> 18) * 16 + ql];
        b0 += bf_lo(v.x) * g.x;  b1 += bf_hi(v.x) * g.y;
        b2 += bf_lo(v.y) * g.z;  b3 += bf_hi(v.y) * g.w;
    }
    a0 += b0; a1 += b1; a2 += b2; a3 += b3;
    a0 += __shfl_xor(a0, 16);          // merge the two duo slots (within half)
    a1 += __shfl_xor(a1, 16);
    a2 += __shfl_xor(a2, 16);
    a3 += __shfl_xor(a3, 16);

    float deg = fmaxf((float)(end - beg), 1.0f);
    float4 xv = ((const float4*)entity_emb)[(long)ent * 16 + ql];
    float v0 = a0 / deg + xv.x;
    float v1 = a1 / deg + xv.y;
    float v2 = a2 / deg + xv.z;
    float v3 = a3 / deg + xv.w;
    v0 = (v0 > 0.0f) ? v0 : (__expf(v0) - 1.0f);
    v1 = (v1 > 0.0f) ? v1 : (__expf(v1) - 1.0f);
    v2 = (v2 > 0.0f) ? v2 : (__expf(v2) - 1.0f);
    v3 = (v3 > 0.0f) ? v3 : (__expf(v3) - 1.0f);
    float ss = v0 * v0 + v1 * v1 + v2 * v2 + v3 * v3;
    ss += __shfl_xor(ss, 1);
    ss += __shfl_xor(ss, 2);
    ss += __shfl_xor(ss, 4);
    ss += __shfl_xor(ss, 8);
    float inv = 1.0f / fmaxf(sqrtf(ss), 1e-12f);
    if (duo == 0) {
        float r0 = v0 * inv, r1 = v1 * inv, r2 = v2 * inv, r3 = v3 * inv;
        ((float4*)all_emb)[(long)w * 16 + ql] = make_float4(r0, r1, r2, r3);
        ((uint2*)all16)[(long)w * 16 + ql] =
            make_uint2((unsigned)f2bf(r0) | ((unsigned)f2bf(r1) << 16),
                       (unsigned)f2bf(r2) | ((unsigned)f2bf(r3) << 16));
    }
}

// ---------------------------------------------------------------------------
// ui_aggregate_s: TWO SAMPLE ROWS PER WAVE (same half-wave transform).
// ---------------------------------------------------------------------------
__global__ __launch_bounds__(256) void ui_aggregate_s(const int* __restrict__ off,
                                                      const int* __restrict__ colrec,
                                                      const float* __restrict__ uval,
                                                      const float* __restrict__ all_emb,
                                                      const float* __restrict__ user_emb,
                                                      const unsigned short* __restrict__ all16,
                                                      const int* __restrict__ u,
                                                      const int* __restrict__ ipos,
                                                      const int* __restrict__ ineg,
                                                      float* __restrict__ final_emb, int B) {
    const uint2* a2p = (const uint2*)all16;
    int lane = threadIdx.x & 63;
    int half = lane >> 5;
    int hl   = lane & 31;
    int duo  = hl >> 4;
    int ql   = hl & 15;
    long wpair = (long)((blockIdx.x * 256 + threadIdx.x) >> 6);
    int s = (int)(wpair * 2 + half);
    if (s >= 3 * B) return;            // 3B even: whole wave exits together
    int r;
    if (s < B)          r = u[s];
    else if (s < 2 * B) r = N_USERS + ipos[s - B];
    else                r = N_USERS + ineg[s - 2 * B];

    int beg = off[r], end = off[r + 1];
    float a0 = 0.f, a1 = 0.f, a2 = 0.f, a3 = 0.f;
    float b0 = 0.f, b1 = 0.f, b2 = 0.f, b3 = 0.f;
    int p = beg;
    for (; p + 4 <= end; p += 4) {
        int   c0 = colrec[p + duo];
        int   c1 = colrec[p + 2 + duo];
        float d0 = uval[p + duo];
        float d1 = uval[p + 2 + duo];
        uint2 v0 = a2p[(long)c0 * 16 + ql];
        uint2 v1 = a2p[(long)c1 * 16 + ql];
        a0 += d0 * bf_lo(v0.x);  a1 += d0 * bf_hi(v0.x);
        a2 += d0 * bf_lo(v0.y);  a3 += d0 * bf_hi(v0.y);
        b0 += d1 * bf_lo(v1.x);  b1 += d1 * bf_hi(v1.x);
        b2 += d1 * bf_lo(v1.y);  b3 += d1 * bf_hi(v1.y);
    }
    if (p + duo < end) {
        int   c = colrec[p + duo];
        float d = uval[p + duo];
        uint2 v = a2p[(long)c * 16 + ql];
        a0 += d * bf_lo(v.x);  a1 += d * bf_hi(v.x);
        a2 += d * bf_lo(v.y);  a3 += d * bf_hi(v.y);
    }
    if (p + 2 + duo < end) {
        int   c = colrec[p + 2 + duo];
        float d = uval[p + 2 + duo];
        uint2 v = a2p[(long)c * 16 + ql];
        b0 += d * bf_lo(v.x);  b1 += d * bf_hi(v.x);
        b2 += d * bf_lo(v.y);  b3 += d * bf_hi(v.y);
    }
    a0 += b0; a1 += b1; a2 += b2; a3 += b3;
    a0 += __shfl_xor(a0, 16);
    a1 += __shfl_xor(a1, 16);
    a2 += __shfl_xor(a2, 16);
    a3 += __shfl_xor(a3, 16);
    if (duo == 0) {
        float4 ae = (r < N_USERS)
            ? ((const float4*)user_emb)[(long)r * 16 + ql]
            : ((const float4*)all_emb)[(long)r * 16 + ql];
        ((float4*)final_emb)[(long)r * 16 + ql] =
            make_float4(0.5f * (ae.x + a0), 0.5f * (ae.y + a1),
                        0.5f * (ae.z + a2), 0.5f * (ae.w + a3));
    }
}

// ---------------------------------------------------------------------------
// Epilogue (intent folded in): one wave per sample.
// ---------------------------------------------------------------------------
__global__ void final_kernel(const int* __restrict__ u, const int* __restrict__ ipos,
                             const int* __restrict__ ineg,
                             const float* __restrict__ final_emb,
                             const float* __restrict__ all_emb,
                             const float* __restrict__ rw, const float* __restrict__ rb,
                             const float* __restrict__ iw, const float* __restrict__ rel_emb,
                             float* __restrict__ out, int B) {
    __shared__ float sh_intent[128];
    if (threadIdx.x < 64) {
        int j = threadIdx.x;
        for (int k = 0; k < 2; k++) {
            float m = -1e30f;
            for (int r = 0; r < N_REL; r++) m = fmaxf(m, iw[k * N_REL + r]);
            float Z = 0.f, acc = 0.f;
            for (int r = 0; r < N_REL; r++) {
                float e = __expf(iw[k * N_REL + r] - m);
                Z += e;
                acc += e * rel_emb[r * 64 + j];
            }
            sh_intent[k * 64 + j] = acc / Z;
        }
    }
    __syncthreads();
    int lane = threadIdx.x & 63;
    int wave = (blockIdx.x * blockDim.x + threadIdx.x) >> 6;
    int nw   = (gridDim.x * blockDim.x) >> 6;
    for (int b = wave; b < B; b += nw) {
        int uu = u[b];
        float up = final_emb[(long)uu * 64 + lane];
        float l0 = up * rw[lane];
        float l1 = up * rw[64 + lane];
        #pragma unroll
        for (int o = 32; o; o >>= 1) {
            l0 += __shfl_xor(l0, o);
            l1 += __shfl_xor(l1, o);
        }
        l0 += rb[0]; l1 += rb[1];
        float m  = fmaxf(l0, l1);
        float e0 = __expf(l0 - m), e1 = __expf(l1 - m);
        float inv = 1.0f / (e0 + e1);
        float p0 = e0 * inv, p1 = e1 * inv;
        float ue = up + p0 * sh_intent[lane] + p1 * sh_intent[64 + lane];

        int it = ipos[b];
        long rr = (long)(N_USERS + it) * 64 + lane;
        float ie = final_emb[rr] + all_emb[rr];
        float dp = ue * ie;
        #pragma unroll
        for (int o = 32; o; o >>= 1) dp += __shfl_xor(dp, o);
        if (lane == 0) out[b] = dp;

        it = ineg[b];
        rr = (long)(N_USERS + it) * 64 + lane;
        ie = final_emb[rr] + all_emb[rr];
        dp = ue * ie;
        #pragma unroll
        for (int o = 32; o; o >>= 1) dp += __shfl_xor(dp, o);
        if (lane == 0) out[B + b] = dp;
    }
}

extern "C" void kernel_launch(void* const* d_in, const int* in_sizes, int n_in,
                              void* d_out, int out_size, void* d_ws, size_t ws_size,
                              hipStream_t stream) {
    const int*   u          = (const int*)  d_in[0];
    const int*   ipos       = (const int*)  d_in[1];
    const int*   ineg       = (const int*)  d_in[2];
    const float* user_emb   = (const float*)d_in[3];
    const float* entity_emb = (const float*)d_in[4];
    const float* rel_emb    = (const float*)d_in[5];
    const float* iw         = (const float*)d_in[6];
    const float* rw         = (const float*)d_in[7];
    const float* rb         = (const float*)d_in[8];
    const float* kgw        = (const float*)d_in[9];
    const float* ui_vals    = (const float*)d_in[10];
    const int*   i2e        = (const int*)  d_in[11];
    const int*   kg_src     = (const int*)  d_in[12];
    const int*   kg_dst     = (const int*)  d_in[13];
    const int*   kg_rel     = (const int*)  d_in[14];
    const int*   ui_row     = (const int*)  d_in[15];
    const int*   ui_col     = (const int*)  d_in[16];
    float*       out        = (float*)d_out;

    int B    = in_sizes[0];
    int e_kg = in_sizes[12];
    int e_ui = in_sizes[15];

    // ---------------- workspace layout (bytes) ----------------
    char* ws = (char*)d_ws;
    unsigned short* y16       = (unsigned short*)(ws + 0);        // 25.6 MB
    float*          all_emb   = (float*)(ws + 25600000);          // 38.4 MB
    unsigned short* all16     = (unsigned short*)(ws + 64000000); // 19.2 MB
    float*          final_emb = (float*)(ws + 83200000);          // 38.4 MB (sparse use)
    unsigned int*   kgrec     = (unsigned int*)(ws + 121600000);  // 8 MB
    int*            uirec     = (int*)(ws + 129600000);           // 4 MB
    float*          uval      = (float*)(ws + 133600000);         // 4 MB
    int*            off_kg    = (int*)(ws + 137600000);           // 200001 ints
    int*            off_ui    = (int*)(ws + 138400256);           // 150001 ints
    unsigned*       ent_mask  = (unsigned*)(ws + 139000512);      // 25088 B (200K bits)
    unsigned*       node_mask = (unsigned*)(ws + 139025600);      // 18752 B (150K bits)
    int*            bcnt      = (int*)(ws + 139600512);           // 977 ints
    int*            boff_kg   = (int*)(ws + 139604480);           // 392 ints
    int*            boff_ui   = (int*)(ws + 139606272);           // 587 ints
    int*            bcur      = (int*)(ws + 139608704);           // 977 ints
    float2*         gateg     = (float2*)(ws + 139612672);        // 8 KB gate table

    hipMemsetAsync(ent_mask, 0, 25088 + 18752, stream);   // masks contiguous
    build_masks    <<<512, 256, 0, stream>>>(i2e, u, ipos, ineg, ent_mask, node_mask,
                                             bcnt, B);
    bucket_hist    <<<1024, 256, 0, stream>>>(kg_dst, ui_row, ent_mask, node_mask,
                                              rel_emb, gateg, bcnt, e_kg, e_ui);
    bucket_scan    <<<1,   256, 0, stream>>>(bcnt, boff_kg, boff_ui, bcur);
    bucket_scatter <<<768, 512, 0, stream>>>(kg_src, kg_dst, kg_rel, ui_row, ui_col,
                                             ui_vals, ent_mask, node_mask,
                                             bcur, kgrec, uirec, uval, e_kg, e_ui);
    bucket_finalize<<<NB_TOT, 256, 0, stream>>>(boff_kg, boff_ui, kgrec, uirec, uval,
                                                off_kg, off_ui);

    ent_matmul <<<(N_ENT + 127) / 128, 256, 0, stream>>>(entity_emb, kgw, y16, N_ENT);
    {   // two nodes per wave
        int nwaves = (N_NODES + 1) / 2;
        int nblk   = (nwaves * 64 + 255) / 256;
        kgagg_build<<<nblk, 256, 0, stream>>>(
            off_kg, kgrec, y16, entity_emb, user_emb, i2e, (const float4*)gateg,
            all_emb, all16);
    }
    {   // two sample rows per wave
        int nwaves = (3 * B + 1) / 2;
        int nblk   = (nwaves * 64 + 255) / 256;
        ui_aggregate_s<<<nblk, 256, 0, stream>>>(
            off_ui, uirec, uval, all_emb, user_emb, all16, u, ipos, ineg, final_emb, B);
    }
    final_kernel<<<256, 256, 0, stream>>>(u, ipos, ineg, final_emb, all_emb,
                                          rw, rb, iw, rel_emb, out, B);
}

// Round 9
// 313.798 us; speedup vs baseline: 1.2813x; 1.0533x over previous
//
#include <hip/hip_runtime.h>
#include <math.h>

#define N_USERS 50000
#define N_ITEMS 100000
#define N_ENT   200000
#define N_NODES (N_USERS + N_ITEMS)
#define N_REL   32
#define DIM     64

#define NB_KG  391          // KG buckets: dst>>9 (512 keys each)
#define NB_UI  586          // UI buckets: row>>8 (256 keys each)
#define NB_TOT (NB_KG + NB_UI)   // 977
#define CAPD   4096         // max KEPT edges per bucket (post-filter)
#define NSCAT  768          // scatter blocks inside the fused mm_scatter dispatch

__device__ __forceinline__ unsigned short f2bf(float f) {   // RNE f32->bf16
    unsigned u = __float_as_uint(f);
    u += 0x7FFFu + ((u >> 16) & 1u);
    return (unsigned short)(u >> 16);
}
__device__ __forceinline__ float bf_lo(unsigned v) { return __uint_as_float(v << 16); }
__device__ __forceinline__ float bf_hi(unsigned v) { return __uint_as_float(v & 0xFFFF0000u); }
__device__ __forceinline__ int getbit(const unsigned* m, int i) {
    return (m[i >> 5] >> (i & 31)) & 1;
}

// ---------------------------------------------------------------------------
// mm_scatter: FUSED dispatch. Blocks [0,NSCAT) run the edge scatter (Pass C);
// blocks [NSCAT, NSCAT+1563) run ent_matmul (y16 = bf16(x @ W^T)).
// The two are data-independent and stress disjoint resources (scatter: L2
// atomics + scattered 4B writes, 4% VALU; matmul: LDS/VALU + streaming
// reads) — fusing converts serial sum (~90us) into concurrent max.
// LDS is a union: matmul xt[64][128]+wt[64][64] = 48KB exactly; scatter
// aliases the first 8KB as h/lbase. 3 blocks/CU either way.
// Matmul: 512 threads, 2x8 outputs/thread (24 waves/CU vs R7's 12);
// per-output FMA order k-ascending -> BIT-IDENTICAL numerics.
// Scatter body is R7's proven 512t x 8-edge form, grid-strided by NSCAT.
// ---------------------------------------------------------------------------
__global__ __launch_bounds__(512) void mm_scatter(const float* __restrict__ x,
                                                  const float* __restrict__ w,
                                                  unsigned short* __restrict__ y16,
                                                  int n_ent,
                                                  const int* __restrict__ kg_src,
                                                  const int* __restrict__ kg_dst,
                                                  const int* __restrict__ kg_rel,
                                                  const int* __restrict__ ui_row,
                                                  const int* __restrict__ ui_col,
                                                  const float* __restrict__ ui_vals,
                                                  const unsigned* __restrict__ ent_mask,
                                                  const unsigned* __restrict__ node_mask,
                                                  int* __restrict__ bcur,
                                                  unsigned int* __restrict__ kgrec,
                                                  int* __restrict__ uirec,
                                                  float* __restrict__ uval,
                                                  int e_kg, int e_ui) {
    __shared__ __align__(16) char smem[49152];
    int tid = threadIdx.x;

    if (blockIdx.x < NSCAT) {
        // ---------------- scatter branch ----------------
        int* h     = (int*)smem;
        int* lbase = h + NB_TOT;
        int n = e_kg + e_ui;
        int nchunks = (n + 4095) >> 12;
        for (int c = blockIdx.x; c < nchunks; c += NSCAT) {
            int base = c << 12;
            for (int i = tid; i < NB_TOT; i += 512) h[i] = 0;
            __syncthreads();
            unsigned int rec[8];
            float val[8];
            int bk[8];
            #pragma unroll
            for (int j = 0; j < 8; j++) {
                int e = base + j * 512 + tid;
                bk[j] = -1;
                if (e < n) {
                    if (e < e_kg) {
                        int d = kg_dst[e];
                        if (getbit(ent_mask, d)) {
                            bk[j]  = d >> 9;
                            rec[j] = (unsigned int)kg_src[e]
                                     | ((unsigned int)kg_rel[e] << 18)
                                     | ((unsigned int)(d & 511) << 23);
                            atomicAdd(&h[bk[j]], 1);
                        }
                    } else {
                        int i2 = e - e_kg;
                        int r  = ui_row[i2];
                        if (getbit(node_mask, r)) {
                            bk[j]  = NB_KG + (r >> 8);
                            rec[j] = (unsigned int)ui_col[i2]
                                     | ((unsigned int)(r & 255) << 18);
                            val[j] = ui_vals[i2];
                            atomicAdd(&h[bk[j]], 1);
                        }
                    }
                }
            }
            __syncthreads();
            for (int i = tid; i < NB_TOT; i += 512) {
                int cc = h[i];
                lbase[i] = cc ? atomicAdd(&bcur[i], cc) : 0;
            }
            __syncthreads();
            #pragma unroll
            for (int j = 0; j < 8; j++) {
                if (bk[j] >= 0) {
                    int pos = atomicAdd(&lbase[bk[j]], 1);
                    if (bk[j] < NB_KG) kgrec[pos] = rec[j];
                    else               { uirec[pos] = (int)rec[j]; uval[pos] = val[j]; }
                }
            }
            __syncthreads();
        }
        return;
    }

    // ---------------- matmul branch ----------------
    float (*xt)[128] = (float (*)[128])smem;            // 32768 B
    float (*wt)[64]  = (float (*)[64])(smem + 32768);   // 16384 B
    int base = (blockIdx.x - NSCAT) * 128;

    #pragma unroll
    for (int q = 0; q < 2; q++) {
        int idx = q * 512 + tid;          // 1024 float4 of w
        int j = idx >> 4, k4 = idx & 15;
        int s0 = (k4 << 2) & 28;          // sigma for rows 4k4..4k4+3
        float4 v = ((const float4*)w)[idx];
        wt[4 * k4 + 0][j ^ s0] = v.x;
        wt[4 * k4 + 1][j ^ s0] = v.y;
        wt[4 * k4 + 2][j ^ s0] = v.z;
        wt[4 * k4 + 3][j ^ s0] = v.w;
    }
    #pragma unroll
    for (int q = 0; q < 4; q++) {
        int idx = q * 512 + tid;          // 2048 float4 of x
        int r = idx >> 4, k4 = idx & 15;
        int gr = base + r;
        int s0 = (k4 << 2) & 28;
        if (gr < n_ent) {
            float4 v = ((const float4*)x)[(long)gr * 16 + k4];
            xt[4 * k4 + 0][r ^ s0] = v.x;
            xt[4 * k4 + 1][r ^ s0] = v.y;
            xt[4 * k4 + 2][r ^ s0] = v.z;
            xt[4 * k4 + 3][r ^ s0] = v.w;
        }
    }
    __syncthreads();

    int j0 = (tid & 7) * 8;               // 8 output cols
    int r0 = (tid >> 3) * 2;              // 2 output rows (0..126)
    float acc[2][8];
    #pragma unroll
    for (int i = 0; i < 2; i++)
        #pragma unroll
        for (int j = 0; j < 8; j++) acc[i][j] = 0.f;

    #pragma unroll 4
    for (int k = 0; k < 64; k++) {
        int s = k & 28;
        // swizzle bits 2-4, r0 even -> (r0^s) even, (r0+1)^s = (r0^s)+1
        float2 xa = *(const float2*)&xt[k][r0 ^ s];
        float4 wa = *(const float4*)&wt[k][j0 ^ s];
        float4 wb = *(const float4*)&wt[k][(j0 + 4) ^ s];
        float xr[2] = {xa.x, xa.y};
        float wr[8] = {wa.x, wa.y, wa.z, wa.w, wb.x, wb.y, wb.z, wb.w};
        #pragma unroll
        for (int i = 0; i < 2; i++)
            #pragma unroll
            for (int j = 0; j < 8; j++)
                acc[i][j] += xr[i] * wr[j];
    }

    #pragma unroll
    for (int i = 0; i < 2; i++) {
        int gr = base + r0 + i;
        if (gr < n_ent) {
            uint4 o;
            o.x = (unsigned)f2bf(acc[i][0]) | ((unsigned)f2bf(acc[i][1]) << 16);
            o.y = (unsigned)f2bf(acc[i][2]) | ((unsigned)f2bf(acc[i][3]) << 16);
            o.z = (unsigned)f2bf(acc[i][4]) | ((unsigned)f2bf(acc[i][5]) << 16);
            o.w = (unsigned)f2bf(acc[i][6]) | ((unsigned)f2bf(acc[i][7]) << 16);
            *(uint4*)&y16[(long)gr * 64 + j0] = o;
        }
    }
}

// ---------------------------------------------------------------------------
// build_masks: membership bitmaps + zero bcnt.
// ---------------------------------------------------------------------------
__global__ __launch_bounds__(256) void build_masks(const int* __restrict__ i2e,
                                                   const int* __restrict__ u,
                                                   const int* __restrict__ ipos,
                                                   const int* __restrict__ ineg,
                                                   unsigned* __restrict__ ent_mask,
                                                   unsigned* __restrict__ node_mask,
                                                   int* __restrict__ bcnt,
                                                   int B) {
    int t = blockIdx.x * 256 + threadIdx.x;
    int stride = gridDim.x * 256;
    for (int i = threadIdx.x; i < NB_TOT; i += 256) bcnt[i] = 0;
    for (int i = t; i < N_ITEMS; i += stride) {
        int e = i2e[i];
        atomicOr(&ent_mask[e >> 5], 1u << (e & 31));
    }
    for (int i = t; i < 3 * B; i += stride) {
        int r = (i < B) ? u[i]
              : (i < 2 * B) ? N_USERS + ipos[i - B]
                            : N_USERS + ineg[i - 2 * B];
        atomicOr(&node_mask[r >> 5], 1u << (r & 31));
    }
}

// ---------------------------------------------------------------------------
// Pass A: per-block LDS bucket histogram over KEPT edges only.
// Block 0 additionally precomputes the sigmoid gate table ONCE into gateg.
// ---------------------------------------------------------------------------
__global__ __launch_bounds__(256) void bucket_hist(const int* __restrict__ kg_dst,
                                                   const int* __restrict__ ui_row,
                                                   const unsigned* __restrict__ ent_mask,
                                                   const unsigned* __restrict__ node_mask,
                                                   const float* __restrict__ rel_emb,
                                                   float2* __restrict__ gateg,
                                                   int* __restrict__ bcnt,
                                                   int e_kg, int e_ui) {
    __shared__ int h[NB_TOT];
    for (int i = threadIdx.x; i < NB_TOT; i += 256) h[i] = 0;
    __syncthreads();
    if (blockIdx.x == 0) {
        for (int idx = threadIdx.x; idx < N_REL * 32; idx += 256) {
            int rel = idx >> 5, hl2 = idx & 31;
            float g0 = 1.0f / (1.0f + __expf(-rel_emb[rel * 64 + 2 * hl2]));
            float g1 = 1.0f / (1.0f + __expf(-rel_emb[rel * 64 + 2 * hl2 + 1]));
            gateg[idx] = make_float2(g0, g1);
        }
    }
    int n = e_kg + e_ui;
    int t = blockIdx.x * 256 + threadIdx.x;
    int stride = gridDim.x * 256;
    for (int e = t; e < n; e += stride) {
        int bk;
        if (e < e_kg) {
            int d = kg_dst[e];
            if (!getbit(ent_mask, d)) continue;
            bk = d >> 9;
        } else {
            int r = ui_row[e - e_kg];
            if (!getbit(node_mask, r)) continue;
            bk = NB_KG + (r >> 8);
        }
        atomicAdd(&h[bk], 1);
    }
    __syncthreads();
    for (int i = threadIdx.x; i < NB_TOT; i += 256)
        if (h[i]) atomicAdd(&bcnt[i], h[i]);
}

// ---------------------------------------------------------------------------
// Pass B: exclusive scan of bucket counts. boff[NB] = total KEPT edges.
// ---------------------------------------------------------------------------
__global__ __launch_bounds__(256) void bucket_scan(const int* __restrict__ bcnt,
                                                   int* __restrict__ boff_kg,
                                                   int* __restrict__ boff_ui,
                                                   int* __restrict__ bcur) {
    __shared__ int sh[1024];
    int t = threadIdx.x;
    for (int seg = 0; seg < 2; seg++) {
        int NB = seg ? NB_UI : NB_KG;
        const int* src = bcnt + (seg ? NB_KG : 0);
        int idx[4] = { t, t + 256, t + 512, t + 768 };
        int v[4];
        #pragma unroll
        for (int q = 0; q < 4; q++) {
            v[q] = (idx[q] < NB) ? src[idx[q]] : 0;
            sh[idx[q]] = v[q];
        }
        __syncthreads();
        for (int o = 1; o < 1024; o <<= 1) {
            int a[4];
            #pragma unroll
            for (int q = 0; q < 4; q++) a[q] = (idx[q] >= o) ? sh[idx[q] - o] : 0;
            __syncthreads();
            #pragma unroll
            for (int q = 0; q < 4; q++) sh[idx[q]] += a[q];
            __syncthreads();
        }
        int* boff = seg ? boff_ui : boff_kg;
        int  base = seg ? NB_KG : 0;
        #pragma unroll
        for (int q = 0; q < 4; q++) {
            if (idx[q] < NB) {
                int ex = sh[idx[q]] - v[q];
                boff[idx[q]] = ex;
                bcur[base + idx[q]] = ex;
                if (idx[q] == NB - 1) boff[NB] = sh[idx[q]];
            }
        }
        __syncthreads();
    }
}

// ---------------------------------------------------------------------------
// Pass D: one block per bucket. LDS counting-sort of KEPT records.
// ---------------------------------------------------------------------------
__global__ __launch_bounds__(256) void bucket_finalize(const int* __restrict__ boff_kg,
                                                       const int* __restrict__ boff_ui,
                                                       unsigned int* __restrict__ kgrec,
                                                       int* __restrict__ uirec,
                                                       float* __restrict__ uval,
                                                       int* __restrict__ off_kg,
                                                       int* __restrict__ off_ui) {
    __shared__ unsigned int rec[CAPD];
    __shared__ float fval[CAPD];
    __shared__ int hist[512];
    bool iskg = blockIdx.x < NB_KG;
    int  b    = iskg ? blockIdx.x : blockIdx.x - NB_KG;
    const int* boff = iskg ? boff_kg : boff_ui;
    int ebeg = boff[b], eend = boff[b + 1];
    int ne   = min(eend - ebeg, CAPD);
    int key_base = iskg ? (b << 9) : (b << 8);
    int nkeys = iskg ? min(512, N_ENT - key_base) : min(256, N_NODES - key_base);
    int SH = iskg ? 23 : 18;
    int tid = threadIdx.x;

    for (int i = tid; i < ne; i += 256) {
        if (iskg) rec[i] = kgrec[ebeg + i];
        else { rec[i] = (unsigned int)uirec[ebeg + i]; fval[i] = uval[ebeg + i]; }
    }
    for (int i = tid; i < 512; i += 256) hist[i] = 0;
    __syncthreads();
    for (int i = tid; i < ne; i += 256)
        atomicAdd(&hist[rec[i] >> SH], 1);
    __syncthreads();
    int i0 = tid, i1 = tid + 256;
    int v0 = hist[i0], v1 = hist[i1];
    __syncthreads();
    for (int o = 1; o < 512; o <<= 1) {
        int a0 = (i0 >= o) ? hist[i0 - o] : 0;
        int a1 = (i1 >= o) ? hist[i1 - o] : 0;
        __syncthreads();
        hist[i0] += a0; hist[i1] += a1;
        __syncthreads();
    }
    int e0 = hist[i0] - v0, e1 = hist[i1] - v1;
    __syncthreads();
    hist[i0] = e0; hist[i1] = e1;
    int* offg = iskg ? off_kg : off_ui;
    if (i0 < nkeys) offg[key_base + i0] = ebeg + e0;
    if (i1 < nkeys) offg[key_base + i1] = ebeg + e1;
    if (blockIdx.x == 0 && tid == 0) {
        off_kg[N_ENT]   = boff_kg[NB_KG];
        off_ui[N_NODES] = boff_ui[NB_UI];
    }
    __syncthreads();
    for (int i = tid; i < ne; i += 256) {
        unsigned int r = rec[i];
        int k = r >> SH;
        int slot = atomicAdd(&hist[k], 1);
        if (iskg) kgrec[ebeg + slot] = r & 0x7FFFFFu;
        else      { uirec[ebeg + slot] = (int)(r & 0x3FFFFu); uval[ebeg + slot] = fval[i]; }
    }
}

// ---------------------------------------------------------------------------
// kgagg_build: TWO NODES PER WAVE, one per half-wave (32 lanes).
// Half layout: 16 lanes x uint2 per row (dims 4ql..4ql+3), 2 edge slots.
// f32 all_emb written only for node_mask-marked item rows (the only rows
// ui_aggregate/final ever read) — saves ~23MB of the 25.6MB f32 write.
// ---------------------------------------------------------------------------
__global__ __launch_bounds__(256) void kgagg_build(const int* __restrict__ off,
                                                   const unsigned int* __restrict__ packed,
                                                   const unsigned short* __restrict__ y16,
                                                   const float* __restrict__ entity_emb,
                                                   const float* __restrict__ user_emb,
                                                   const int* __restrict__ i2e,
                                                   const float4* __restrict__ gate4,
                                                   const unsigned* __restrict__ node_mask,
                                                   float* __restrict__ all_emb,
                                                   unsigned short* __restrict__ all16) {
    int lane = threadIdx.x & 63;
    int half = lane >> 5;          // which node of the pair
    int hl   = lane & 31;
    int duo  = hl >> 4;            // edge slot within half
    int ql   = hl & 15;            // dims 4ql..4ql+3
    long wpair = (long)((blockIdx.x * 256 + threadIdx.x) >> 6);
    int w = (int)(wpair * 2 + half);
    if (w >= N_NODES) return;      // N_NODES even: whole wave exits together

    if (w < N_USERS) {             // both halves users: bf16 copy only
        if (duo == 0) {
            float4 v = ((const float4*)user_emb)[(long)w * 16 + ql];
            ((uint2*)all16)[(long)w * 16 + ql] =
                make_uint2((unsigned)f2bf(v.x) | ((unsigned)f2bf(v.y) << 16),
                           (unsigned)f2bf(v.z) | ((unsigned)f2bf(v.w) << 16));
        }
        return;
    }

    int ent = i2e[w - N_USERS];    // half-uniform (broadcast load)
    const uint2* y2 = (const uint2*)y16;
    int beg = off[ent], end = off[ent + 1];
    float a0 = 0.f, a1 = 0.f, a2 = 0.f, a3 = 0.f;
    float b0 = 0.f, b1 = 0.f, b2 = 0.f, b3 = 0.f;
    int p = beg;
    for (; p + 4 <= end; p += 4) {     // 4 edges per half per iter
        unsigned pk0 = packed[p + duo];
        unsigned pk1 = packed[p + 2 + duo];
        uint2 v0 = y2[(long)(pk0 & 0x3FFFF) * 16 + ql];
        uint2 v1 = y2[(long)(pk1 & 0x3FFFF) * 16 + ql];
        float4 g0 = gate4[(pk0 >> 18) * 16 + ql];
        float4 g1 = gate4[(pk1 >> 18) * 16 + ql];
        a0 += bf_lo(v0.x) * g0.x;  a1 += bf_hi(v0.x) * g0.y;
        a2 += bf_lo(v0.y) * g0.z;  a3 += bf_hi(v0.y) * g0.w;
        b0 += bf_lo(v1.x) * g1.x;  b1 += bf_hi(v1.x) * g1.y;
        b2 += bf_lo(v1.y) * g1.z;  b3 += bf_hi(v1.y) * g1.w;
    }
    if (p + duo < end) {               // tail edges p..p+1
        unsigned pk = packed[p + duo];
        uint2 v = y2[(long)(pk & 0x3FFFF) * 16 + ql];
        float4 g = gate4[(pk >> 18) * 16 + ql];
        a0 += bf_lo(v.x) * g.x;  a1 += bf_hi(v.x) * g.y;
        a2 += bf_lo(v.y) * g.z;  a3 += bf_hi(v.y) * g.w;
    }
    if (p + 2 + duo < end) {           // tail edge p+2 (p+3 impossible)
        unsigned pk = packed[p + 2 + duo];
        uint2 v = y2[(long)(pk & 0x3FFFF) * 16 + ql];
        float4 g = gate4[(pk >> 18) * 16 + ql];
        b0 += bf_lo(v.x) * g.x;  b1 += bf_hi(v.x) * g.y;
        b2 += bf_lo(v.y) * g.z;  b3 += bf_hi(v.y) * g.w;
    }
    a0 += b0; a1 += b1; a2 += b2; a3 += b3;
    a0 += __shfl_xor(a0, 16);          // merge the two duo slots (within half)
    a1 += __shfl_xor(a1, 16);
    a2 += __shfl_xor(a2, 16);
    a3 += __shfl_xor(a3, 16);

    float deg = fmaxf((float)(end - beg), 1.0f);
    float4 xv = ((const float4*)entity_emb)[(long)ent * 16 + ql];
    float v0 = a0 / deg + xv.x;
    float v1 = a1 / deg + xv.y;
    float v2 = a2 / deg + xv.z;
    float v3 = a3 / deg + xv.w;
    v0 = (v0 > 0.0f) ? v0 : (__expf(v0) - 1.0f);
    v1 = (v1 > 0.0f) ? v1 : (__expf(v1) - 1.0f);
    v2 = (v2 > 0.0f) ? v2 : (__expf(v2) - 1.0f);
    v3 = (v3 > 0.0f) ? v3 : (__expf(v3) - 1.0f);
    float ss = v0 * v0 + v1 * v1 + v2 * v2 + v3 * v3;
    ss += __shfl_xor(ss, 1);
    ss += __shfl_xor(ss, 2);
    ss += __shfl_xor(ss, 4);
    ss += __shfl_xor(ss, 8);
    float inv = 1.0f / fmaxf(sqrtf(ss), 1e-12f);
    if (duo == 0) {
        float r0 = v0 * inv, r1 = v1 * inv, r2 = v2 * inv, r3 = v3 * inv;
        if (getbit(node_mask, w))
            ((float4*)all_emb)[(long)w * 16 + ql] = make_float4(r0, r1, r2, r3);
        ((uint2*)all16)[(long)w * 16 + ql] =
            make_uint2((unsigned)f2bf(r0) | ((unsigned)f2bf(r1) << 16),
                       (unsigned)f2bf(r2) | ((unsigned)f2bf(r3) << 16));
    }
}

// ---------------------------------------------------------------------------
// ui_aggregate_s: TWO SAMPLE ROWS PER WAVE (same half-wave transform).
// ---------------------------------------------------------------------------
__global__ __launch_bounds__(256) void ui_aggregate_s(const int* __restrict__ off,
                                                      const int* __restrict__ colrec,
                                                      const float* __restrict__ uval,
                                                      const float* __restrict__ all_emb,
                                                      const float* __restrict__ user_emb,
                                                      const unsigned short* __restrict__ all16,
                                                      const int* __restrict__ u,
                                                      const int* __restrict__ ipos,
                                                      const int* __restrict__ ineg,
                                                      float* __restrict__ final_emb, int B) {
    const uint2* a2p = (const uint2*)all16;
    int lane = threadIdx.x & 63;
    int half = lane >> 5;
    int hl   = lane & 31;
    int duo  = hl >> 4;
    int ql   = hl & 15;
    long wpair = (long)((blockIdx.x * 256 + threadIdx.x) >> 6);
    int s = (int)(wpair * 2 + half);
    if (s >= 3 * B) return;            // 3B even: whole wave exits together
    int r;
    if (s < B)          r = u[s];
    else if (s < 2 * B) r = N_USERS + ipos[s - B];
    else                r = N_USERS + ineg[s - 2 * B];

    int beg = off[r], end = off[r + 1];
    float a0 = 0.f, a1 = 0.f, a2 = 0.f, a3 = 0.f;
    float b0 = 0.f, b1 = 0.f, b2 = 0.f, b3 = 0.f;
    int p = beg;
    for (; p + 4 <= end; p += 4) {
        int   c0 = colrec[p + duo];
        int   c1 = colrec[p + 2 + duo];
        float d0 = uval[p + duo];
        float d1 = uval[p + 2 + duo];
        uint2 v0 = a2p[(long)c0 * 16 + ql];
        uint2 v1 = a2p[(long)c1 * 16 + ql];
        a0 += d0 * bf_lo(v0.x);  a1 += d0 * bf_hi(v0.x);
        a2 += d0 * bf_lo(v0.y);  a3 += d0 * bf_hi(v0.y);
        b0 += d1 * bf_lo(v1.x);  b1 += d1 * bf_hi(v1.x);
        b2 += d1 * bf_lo(v1.y);  b3 += d1 * bf_hi(v1.y);
    }
    if (p + duo < end) {
        int   c = colrec[p + duo];
        float d = uval[p + duo];
        uint2 v = a2p[(long)c * 16 + ql];
        a0 += d * bf_lo(v.x);  a1 += d * bf_hi(v.x);
        a2 += d * bf_lo(v.y);  a3 += d * bf_hi(v.y);
    }
    if (p + 2 + duo < end) {
        int   c = colrec[p + 2 + duo];
        float d = uval[p + 2 + duo];
        uint2 v = a2p[(long)c * 16 + ql];
        b0 += d * bf_lo(v.x);  b1 += d * bf_hi(v.x);
        b2 += d * bf_lo(v.y);  b3 += d * bf_hi(v.y);
    }
    a0 += b0; a1 += b1; a2 += b2; a3 += b3;
    a0 += __shfl_xor(a0, 16);
    a1 += __shfl_xor(a1, 16);
    a2 += __shfl_xor(a2, 16);
    a3 += __shfl_xor(a3, 16);
    if (duo == 0) {
        float4 ae = (r < N_USERS)
            ? ((const float4*)user_emb)[(long)r * 16 + ql]
            : ((const float4*)all_emb)[(long)r * 16 + ql];
        ((float4*)final_emb)[(long)r * 16 + ql] =
            make_float4(0.5f * (ae.x + a0), 0.5f * (ae.y + a1),
                        0.5f * (ae.z + a2), 0.5f * (ae.w + a3));
    }
}

// ---------------------------------------------------------------------------
// Epilogue (intent folded in): one wave per sample.
// ---------------------------------------------------------------------------
__global__ void final_kernel(const int* __restrict__ u, const int* __restrict__ ipos,
                             const int* __restrict__ ineg,
                             const float* __restrict__ final_emb,
                             const float* __restrict__ all_emb,
                             const float* __restrict__ rw, const float* __restrict__ rb,
                             const float* __restrict__ iw, const float* __restrict__ rel_emb,
                             float* __restrict__ out, int B) {
    __shared__ float sh_intent[128];
    if (threadIdx.x < 64) {
        int j = threadIdx.x;
        for (int k = 0; k < 2; k++) {
            float m = -1e30f;
            for (int r = 0; r < N_REL; r++) m = fmaxf(m, iw[k * N_REL + r]);
            float Z = 0.f, acc = 0.f;
            for (int r = 0; r < N_REL; r++) {
                float e = __expf(iw[k * N_REL + r] - m);
                Z += e;
                acc += e * rel_emb[r * 64 + j];
            }
            sh_intent[k * 64 + j] = acc / Z;
        }
    }
    __syncthreads();
    int lane = threadIdx.x & 63;
    int wave = (blockIdx.x * blockDim.x + threadIdx.x) >> 6;
    int nw   = (gridDim.x * blockDim.x) >> 6;
    for (int b = wave; b < B; b += nw) {
        int uu = u[b];
        float up = final_emb[(long)uu * 64 + lane];
        float l0 = up * rw[lane];
        float l1 = up * rw[64 + lane];
        #pragma unroll
        for (int o = 32; o; o >>= 1) {
            l0 += __shfl_xor(l0, o);
            l1 += __shfl_xor(l1, o);
        }
        l0 += rb[0]; l1 += rb[1];
        float m  = fmaxf(l0, l1);
        float e0 = __expf(l0 - m), e1 = __expf(l1 - m);
        float inv = 1.0f / (e0 + e1);
        float p0 = e0 * inv, p1 = e1 * inv;
        float ue = up + p0 * sh_intent[lane] + p1 * sh_intent[64 + lane];

        int it = ipos[b];
        long rr = (long)(N_USERS + it) * 64 + lane;
        float ie = final_emb[rr] + all_emb[rr];
        float dp = ue * ie;
        #pragma unroll
        for (int o = 32; o; o >>= 1) dp += __shfl_xor(dp, o);
        if (lane == 0) out[b] = dp;

        it = ineg[b];
        rr = (long)(N_USERS + it) * 64 + lane;
        ie = final_emb[rr] + all_emb[rr];
        dp = ue * ie;
        #pragma unroll
        for (int o = 32; o; o >>= 1) dp += __shfl_xor(dp, o);
        if (lane == 0) out[B + b] = dp;
    }
}

extern "C" void kernel_launch(void* const* d_in, const int* in_sizes, int n_in,
                              void* d_out, int out_size, void* d_ws, size_t ws_size,
                              hipStream_t stream) {
    const int*   u          = (const int*)  d_in[0];
    const int*   ipos       = (const int*)  d_in[1];
    const int*   ineg       = (const int*)  d_in[2];
    const float* user_emb   = (const float*)d_in[3];
    const float* entity_emb = (const float*)d_in[4];
    const float* rel_emb    = (const float*)d_in[5];
    const float* iw         = (const float*)d_in[6];
    const float* rw         = (const float*)d_in[7];
    const float* rb         = (const float*)d_in[8];
    const float* kgw        = (const float*)d_in[9];
    const float* ui_vals    = (const float*)d_in[10];
    const int*   i2e        = (const int*)  d_in[11];
    const int*   kg_src     = (const int*)  d_in[12];
    const int*   kg_dst     = (const int*)  d_in[13];
    const int*   kg_rel     = (const int*)  d_in[14];
    const int*   ui_row     = (const int*)  d_in[15];
    const int*   ui_col     = (const int*)  d_in[16];
    float*       out        = (float*)d_out;

    int B    = in_sizes[0];
    int e_kg = in_sizes[12];
    int e_ui = in_sizes[15];

    // ---------------- workspace layout (bytes) ----------------
    char* ws = (char*)d_ws;
    unsigned short* y16       = (unsigned short*)(ws + 0);        // 25.6 MB
    float*          all_emb   = (float*)(ws + 25600000);          // 38.4 MB
    unsigned short* all16     = (unsigned short*)(ws + 64000000); // 19.2 MB
    float*          final_emb = (float*)(ws + 83200000);          // 38.4 MB (sparse use)
    unsigned int*   kgrec     = (unsigned int*)(ws + 121600000);  // 8 MB
    int*            uirec     = (int*)(ws + 129600000);           // 4 MB
    float*          uval      = (float*)(ws + 133600000);         // 4 MB
    int*            off_kg    = (int*)(ws + 137600000);           // 200001 ints
    int*            off_ui    = (int*)(ws + 138400256);           // 150001 ints
    unsigned*       ent_mask  = (unsigned*)(ws + 139000512);      // 25088 B (200K bits)
    unsigned*       node_mask = (unsigned*)(ws + 139025600);      // 18752 B (150K bits)
    int*            bcnt      = (int*)(ws + 139600512);           // 977 ints
    int*            boff_kg   = (int*)(ws + 139604480);           // 392 ints
    int*            boff_ui   = (int*)(ws + 139606272);           // 587 ints
    int*            bcur      = (int*)(ws + 139608704);           // 977 ints
    float2*         gateg     = (float2*)(ws + 139612672);        // 8 KB gate table

    hipMemsetAsync(ent_mask, 0, 25088 + 18752, stream);   // masks contiguous
    build_masks    <<<512, 256, 0, stream>>>(i2e, u, ipos, ineg, ent_mask, node_mask,
                                             bcnt, B);
    bucket_hist    <<<1024, 256, 0, stream>>>(kg_dst, ui_row, ent_mask, node_mask,
                                              rel_emb, gateg, bcnt, e_kg, e_ui);
    bucket_scan    <<<1,   256, 0, stream>>>(bcnt, boff_kg, boff_ui, bcur);
    // Fused: scatter (blocks 0..767) || ent_matmul (blocks 768..2330)
    mm_scatter     <<<NSCAT + (N_ENT + 127) / 128, 512, 0, stream>>>(
        entity_emb, kgw, y16, N_ENT,
        kg_src, kg_dst, kg_rel, ui_row, ui_col, ui_vals,
        ent_mask, node_mask, bcur, kgrec, uirec, uval, e_kg, e_ui);
    bucket_finalize<<<NB_TOT, 256, 0, stream>>>(boff_kg, boff_ui, kgrec, uirec, uval,
                                                off_kg, off_ui);

    {   // two nodes per wave
        int nwaves = (N_NODES + 1) / 2;
        int nblk   = (nwaves * 64 + 255) / 256;
        kgagg_build<<<nblk, 256, 0, stream>>>(
            off_kg, kgrec, y16, entity_emb, user_emb, i2e, (const float4*)gateg,
            node_mask, all_emb, all16);
    }
    {   // two sample rows per wave
        int nwaves = (3 * B + 1) / 2;
        int nblk   = (nwaves * 64 + 255) / 256;
        ui_aggregate_s<<<nblk, 256, 0, stream>>>(
            off_ui, uirec, uval, all_emb, user_emb, all16, u, ipos, ineg, final_emb, B);
    }
    final_kernel<<<256, 256, 0, stream>>>(u, ipos, ineg, final_emb, all_emb,
                                          rw, rb, iw, rel_emb, out, B);
}

// Round 10
// 279.797 us; speedup vs baseline: 1.4370x; 1.1215x over previous
//
#include <hip/hip_runtime.h>
#include <math.h>

#define N_USERS 50000
#define N_ITEMS 100000
#define N_ENT   200000
#define N_NODES (N_USERS + N_ITEMS)
#define N_REL   32
#define DIM     64

#define NB_KG  391          // KG buckets: dst>>9 (512 keys each)
#define NB_UI  586          // UI buckets: row>>8 (256 keys each)
#define NB_TOT (NB_KG + NB_UI)   // 977
#define CAPK   4096         // fixed capacity per KG bucket (max kept ~2700)
#define CAPU   1536         // fixed capacity per UI bucket (max kept ~850)
#define NMMTILE 1563        // ceil(200000/128) matmul tiles
#define NSCAT3  782         // scatter blocks (bid%3==0)
#define FUSE_GRID (NSCAT3 * 3)   // 2346

__device__ __forceinline__ unsigned short f2bf(float f) {   // RNE f32->bf16
    unsigned u = __float_as_uint(f);
    u += 0x7FFFu + ((u >> 16) & 1u);
    return (unsigned short)(u >> 16);
}
__device__ __forceinline__ float bf_lo(unsigned v) { return __uint_as_float(v << 16); }
__device__ __forceinline__ float bf_hi(unsigned v) { return __uint_as_float(v & 0xFFFF0000u); }
__device__ __forceinline__ int getbit(const unsigned* m, int i) {
    return (m[i >> 5] >> (i & 31)) & 1;
}

// ---------------------------------------------------------------------------
// build_masks: membership bitmaps + bcur init (fixed-capacity bucket bases,
// replacing the hist+scan prologue entirely) + gate table (block 0).
// ---------------------------------------------------------------------------
__global__ __launch_bounds__(256) void build_masks(const int* __restrict__ i2e,
                                                   const int* __restrict__ u,
                                                   const int* __restrict__ ipos,
                                                   const int* __restrict__ ineg,
                                                   const float* __restrict__ rel_emb,
                                                   float2* __restrict__ gateg,
                                                   unsigned* __restrict__ ent_mask,
                                                   unsigned* __restrict__ node_mask,
                                                   int* __restrict__ bcur,
                                                   int B) {
    int t = blockIdx.x * 256 + threadIdx.x;
    int stride = gridDim.x * 256;
    for (int i = threadIdx.x; i < NB_TOT; i += 256)          // same-value benign race
        bcur[i] = (i < NB_KG) ? i * CAPK : (i - NB_KG) * CAPU;
    if (blockIdx.x == 0) {
        for (int idx = threadIdx.x; idx < N_REL * 32; idx += 256) {
            int rel = idx >> 5, hl2 = idx & 31;
            float g0 = 1.0f / (1.0f + __expf(-rel_emb[rel * 64 + 2 * hl2]));
            float g1 = 1.0f / (1.0f + __expf(-rel_emb[rel * 64 + 2 * hl2 + 1]));
            gateg[idx] = make_float2(g0, g1);
        }
    }
    for (int i = t; i < N_ITEMS; i += stride) {
        int e = i2e[i];
        atomicOr(&ent_mask[e >> 5], 1u << (e & 31));
    }
    for (int i = t; i < 3 * B; i += stride) {
        int r = (i < B) ? u[i]
              : (i < 2 * B) ? N_USERS + ipos[i - B]
                            : N_USERS + ineg[i - 2 * B];
        atomicOr(&node_mask[r >> 5], 1u << (r & 31));
    }
}

// ---------------------------------------------------------------------------
// mm_scatter: FUSED dispatch, roles INTERLEAVED by blockIdx%3 (R9 fix: the
// old [0,768) scatter prefix filled all concurrent block slots with scatter
// first -> serial phases, 67us). Now every CU gets ~1 scatter + 2 matmul
// blocks from slot 0.
// Scatter writes into fixed-capacity bucket regions (bcur pre-set to bases);
// cap-guards prevent overflow corruption (stat margin >1.5x).
// Matmul: 512 threads, 2x8 out/thread, swizzled 48KB LDS; FMA order
// k-ascending per output -> BIT-IDENTICAL numerics.
// ---------------------------------------------------------------------------
__global__ __launch_bounds__(512) void mm_scatter(const float* __restrict__ x,
                                                  const float* __restrict__ w,
                                                  unsigned short* __restrict__ y16,
                                                  int n_ent,
                                                  const int* __restrict__ kg_src,
                                                  const int* __restrict__ kg_dst,
                                                  const int* __restrict__ kg_rel,
                                                  const int* __restrict__ ui_row,
                                                  const int* __restrict__ ui_col,
                                                  const float* __restrict__ ui_vals,
                                                  const unsigned* __restrict__ ent_mask,
                                                  const unsigned* __restrict__ node_mask,
                                                  int* __restrict__ bcur,
                                                  unsigned int* __restrict__ kgrec,
                                                  int* __restrict__ uirec,
                                                  float* __restrict__ uval,
                                                  int e_kg, int e_ui) {
    __shared__ __align__(16) char smem[49152];
    int tid = threadIdx.x;
    int bid = blockIdx.x;

    if (bid % 3 == 0) {
        // ---------------- scatter branch ----------------
        int* h     = (int*)smem;
        int* lbase = h + NB_TOT;
        int n = e_kg + e_ui;
        int nchunks = (n + 4095) >> 12;
        for (int c = bid / 3; c < nchunks; c += NSCAT3) {
            int base = c << 12;
            for (int i = tid; i < NB_TOT; i += 512) h[i] = 0;
            __syncthreads();
            unsigned int rec[8];
            float val[8];
            int bk[8];
            #pragma unroll
            for (int j = 0; j < 8; j++) {
                int e = base + j * 512 + tid;
                bk[j] = -1;
                if (e < n) {
                    if (e < e_kg) {
                        int d = kg_dst[e];
                        if (getbit(ent_mask, d)) {
                            bk[j]  = d >> 9;
                            rec[j] = (unsigned int)kg_src[e]
                                     | ((unsigned int)kg_rel[e] << 18)
                                     | ((unsigned int)(d & 511) << 23);
                            atomicAdd(&h[bk[j]], 1);
                        }
                    } else {
                        int i2 = e - e_kg;
                        int r  = ui_row[i2];
                        if (getbit(node_mask, r)) {
                            bk[j]  = NB_KG + (r >> 8);
                            rec[j] = (unsigned int)ui_col[i2]
                                     | ((unsigned int)(r & 255) << 18);
                            val[j] = ui_vals[i2];
                            atomicAdd(&h[bk[j]], 1);
                        }
                    }
                }
            }
            __syncthreads();
            for (int i = tid; i < NB_TOT; i += 512) {
                int cc = h[i];
                lbase[i] = cc ? atomicAdd(&bcur[i], cc) : 0;
            }
            __syncthreads();
            #pragma unroll
            for (int j = 0; j < 8; j++) {
                if (bk[j] >= 0) {
                    int pos = atomicAdd(&lbase[bk[j]], 1);
                    if (bk[j] < NB_KG) {
                        if (pos < (bk[j] + 1) * CAPK) kgrec[pos] = rec[j];
                    } else {
                        int bu = bk[j] - NB_KG;
                        if (pos < (bu + 1) * CAPU) { uirec[pos] = (int)rec[j]; uval[pos] = val[j]; }
                    }
                }
            }
            __syncthreads();
        }
        return;
    }

    // ---------------- matmul branch ----------------
    int mtile = bid - bid / 3 - 1;
    if (mtile >= NMMTILE) return;
    float (*xt)[128] = (float (*)[128])smem;            // 32768 B
    float (*wt)[64]  = (float (*)[64])(smem + 32768);   // 16384 B
    int base = mtile * 128;

    #pragma unroll
    for (int q = 0; q < 2; q++) {
        int idx = q * 512 + tid;          // 1024 float4 of w
        int j = idx >> 4, k4 = idx & 15;
        int s0 = (k4 << 2) & 28;          // sigma for rows 4k4..4k4+3
        float4 v = ((const float4*)w)[idx];
        wt[4 * k4 + 0][j ^ s0] = v.x;
        wt[4 * k4 + 1][j ^ s0] = v.y;
        wt[4 * k4 + 2][j ^ s0] = v.z;
        wt[4 * k4 + 3][j ^ s0] = v.w;
    }
    #pragma unroll
    for (int q = 0; q < 4; q++) {
        int idx = q * 512 + tid;          // 2048 float4 of x
        int r = idx >> 4, k4 = idx & 15;
        int gr = base + r;
        int s0 = (k4 << 2) & 28;
        if (gr < n_ent) {
            float4 v = ((const float4*)x)[(long)gr * 16 + k4];
            xt[4 * k4 + 0][r ^ s0] = v.x;
            xt[4 * k4 + 1][r ^ s0] = v.y;
            xt[4 * k4 + 2][r ^ s0] = v.z;
            xt[4 * k4 + 3][r ^ s0] = v.w;
        }
    }
    __syncthreads();

    int j0 = (tid & 7) * 8;               // 8 output cols
    int r0 = (tid >> 3) * 2;              // 2 output rows (0..126)
    float acc[2][8];
    #pragma unroll
    for (int i = 0; i < 2; i++)
        #pragma unroll
        for (int j = 0; j < 8; j++) acc[i][j] = 0.f;

    #pragma unroll 4
    for (int k = 0; k < 64; k++) {
        int s = k & 28;
        float2 xa = *(const float2*)&xt[k][r0 ^ s];
        float4 wa = *(const float4*)&wt[k][j0 ^ s];
        float4 wb = *(const float4*)&wt[k][(j0 + 4) ^ s];
        float xr[2] = {xa.x, xa.y};
        float wr[8] = {wa.x, wa.y, wa.z, wa.w, wb.x, wb.y, wb.z, wb.w};
        #pragma unroll
        for (int i = 0; i < 2; i++)
            #pragma unroll
            for (int j = 0; j < 8; j++)
                acc[i][j] += xr[i] * wr[j];
    }

    #pragma unroll
    for (int i = 0; i < 2; i++) {
        int gr = base + r0 + i;
        if (gr < n_ent) {
            uint4 o;
            o.x = (unsigned)f2bf(acc[i][0]) | ((unsigned)f2bf(acc[i][1]) << 16);
            o.y = (unsigned)f2bf(acc[i][2]) | ((unsigned)f2bf(acc[i][3]) << 16);
            o.z = (unsigned)f2bf(acc[i][4]) | ((unsigned)f2bf(acc[i][5]) << 16);
            o.w = (unsigned)f2bf(acc[i][6]) | ((unsigned)f2bf(acc[i][7]) << 16);
            *(uint4*)&y16[(long)gr * 64 + j0] = o;
        }
    }
}

// ---------------------------------------------------------------------------
// bucket_finalize: one block per bucket, fixed-capacity regions. ne comes
// from bcur (post-scatter cursor minus base). Emits beg[]/end[] arrays
// (end != next beg across bucket boundaries now) + sorted recs in place.
// LDS 24KB (was 34KB): rec[CAPK] + fval[CAPU] + hist.
// ---------------------------------------------------------------------------
__global__ __launch_bounds__(256) void bucket_finalize(const int* __restrict__ bcur,
                                                       unsigned int* __restrict__ kgrec,
                                                       int* __restrict__ uirec,
                                                       float* __restrict__ uval,
                                                       int* __restrict__ beg_kg,
                                                       int* __restrict__ end_kg,
                                                       int* __restrict__ beg_ui,
                                                       int* __restrict__ end_ui) {
    __shared__ unsigned int rec[CAPK];
    __shared__ float fval[CAPU];
    __shared__ int hist[512];
    bool iskg = blockIdx.x < NB_KG;
    int  b    = iskg ? blockIdx.x : blockIdx.x - NB_KG;
    int base  = iskg ? b * CAPK : b * CAPU;
    int cap   = iskg ? CAPK : CAPU;
    int ne    = min(bcur[blockIdx.x] - base, cap);
    int key_base = iskg ? (b << 9) : (b << 8);
    int nkeys = iskg ? min(512, N_ENT - key_base) : min(256, N_NODES - key_base);
    int SH = iskg ? 23 : 18;
    int tid = threadIdx.x;

    for (int i = tid; i < ne; i += 256) {
        if (iskg) rec[i] = kgrec[base + i];
        else { rec[i] = (unsigned int)uirec[base + i]; fval[i] = uval[base + i]; }
    }
    for (int i = tid; i < 512; i += 256) hist[i] = 0;
    __syncthreads();
    for (int i = tid; i < ne; i += 256)
        atomicAdd(&hist[rec[i] >> SH], 1);
    __syncthreads();
    int i0 = tid, i1 = tid + 256;
    int v0 = hist[i0], v1 = hist[i1];
    __syncthreads();
    for (int o = 1; o < 512; o <<= 1) {
        int a0 = (i0 >= o) ? hist[i0 - o] : 0;
        int a1 = (i1 >= o) ? hist[i1 - o] : 0;
        __syncthreads();
        hist[i0] += a0; hist[i1] += a1;
        __syncthreads();
    }
    int e0 = hist[i0] - v0, e1 = hist[i1] - v1;
    __syncthreads();
    hist[i0] = e0; hist[i1] = e1;
    int* begg = iskg ? beg_kg : beg_ui;
    int* endg = iskg ? end_kg : end_ui;
    if (i0 < nkeys) { begg[key_base + i0] = base + e0; endg[key_base + i0] = base + e0 + v0; }
    if (i1 < nkeys) { begg[key_base + i1] = base + e1; endg[key_base + i1] = base + e1 + v1; }
    __syncthreads();
    for (int i = tid; i < ne; i += 256) {
        unsigned int r = rec[i];
        int k = r >> SH;
        int slot = atomicAdd(&hist[k], 1);
        if (iskg) kgrec[base + slot] = r & 0x7FFFFFu;
        else      { uirec[base + slot] = (int)(r & 0x3FFFFu); uval[base + slot] = fval[i]; }
    }
}

// ---------------------------------------------------------------------------
// kgagg_build: TWO NODES PER WAVE, one per half-wave (32 lanes).
// beg/end from separate arrays (fixed-capacity CSR). f32 all_emb written
// only for node_mask-marked item rows.
// ---------------------------------------------------------------------------
__global__ __launch_bounds__(256) void kgagg_build(const int* __restrict__ beg_kg,
                                                   const int* __restrict__ end_kg,
                                                   const unsigned int* __restrict__ packed,
                                                   const unsigned short* __restrict__ y16,
                                                   const float* __restrict__ entity_emb,
                                                   const float* __restrict__ user_emb,
                                                   const int* __restrict__ i2e,
                                                   const float4* __restrict__ gate4,
                                                   const unsigned* __restrict__ node_mask,
                                                   float* __restrict__ all_emb,
                                                   unsigned short* __restrict__ all16) {
    int lane = threadIdx.x & 63;
    int half = lane >> 5;          // which node of the pair
    int hl   = lane & 31;
    int duo  = hl >> 4;            // edge slot within half
    int ql   = hl & 15;            // dims 4ql..4ql+3
    long wpair = (long)((blockIdx.x * 256 + threadIdx.x) >> 6);
    int w = (int)(wpair * 2 + half);
    if (w >= N_NODES) return;      // N_NODES even: whole wave exits together

    if (w < N_USERS) {             // both halves users: bf16 copy only
        if (duo == 0) {
            float4 v = ((const float4*)user_emb)[(long)w * 16 + ql];
            ((uint2*)all16)[(long)w * 16 + ql] =
                make_uint2((unsigned)f2bf(v.x) | ((unsigned)f2bf(v.y) << 16),
                           (unsigned)f2bf(v.z) | ((unsigned)f2bf(v.w) << 16));
        }
        return;
    }

    int ent = i2e[w - N_USERS];    // half-uniform (broadcast load)
    const uint2* y2 = (const uint2*)y16;
    int beg = beg_kg[ent], end = end_kg[ent];
    float a0 = 0.f, a1 = 0.f, a2 = 0.f, a3 = 0.f;
    float b0 = 0.f, b1 = 0.f, b2 = 0.f, b3 = 0.f;
    int p = beg;
    for (; p + 4 <= end; p += 4) {     // 4 edges per half per iter
        unsigned pk0 = packed[p + duo];
        unsigned pk1 = packed[p + 2 + duo];
        uint2 v0 = y2[(long)(pk0 & 0x3FFFF) * 16 + ql];
        uint2 v1 = y2[(long)(pk1 & 0x3FFFF) * 16 + ql];
        float4 g0 = gate4[(pk0 >> 18) * 16 + ql];
        float4 g1 = gate4[(pk1 >> 18) * 16 + ql];
        a0 += bf_lo(v0.x) * g0.x;  a1 += bf_hi(v0.x) * g0.y;
        a2 += bf_lo(v0.y) * g0.z;  a3 += bf_hi(v0.y) * g0.w;
        b0 += bf_lo(v1.x) * g1.x;  b1 += bf_hi(v1.x) * g1.y;
        b2 += bf_lo(v1.y) * g1.z;  b3 += bf_hi(v1.y) * g1.w;
    }
    if (p + duo < end) {               // tail edges p..p+1
        unsigned pk = packed[p + duo];
        uint2 v = y2[(long)(pk & 0x3FFFF) * 16 + ql];
        float4 g = gate4[(pk >> 18) * 16 + ql];
        a0 += bf_lo(v.x) * g.x;  a1 += bf_hi(v.x) * g.y;
        a2 += bf_lo(v.y) * g.z;  a3 += bf_hi(v.y) * g.w;
    }
    if (p + 2 + duo < end) {           // tail edge p+2 (p+3 impossible)
        unsigned pk = packed[p + 2 + duo];
        uint2 v = y2[(long)(pk & 0x3FFFF) * 16 + ql];
        float4 g = gate4[(pk >> 18) * 16 + ql];
        b0 += bf_lo(v.x) * g.x;  b1 += bf_hi(v.x) * g.y;
        b2 += bf_lo(v.y) * g.z;  b3 += bf_hi(v.y) * g.w;
    }
    a0 += b0; a1 += b1; a2 += b2; a3 += b3;
    a0 += __shfl_xor(a0, 16);          // merge the two duo slots (within half)
    a1 += __shfl_xor(a1, 16);
    a2 += __shfl_xor(a2, 16);
    a3 += __shfl_xor(a3, 16);

    float deg = fmaxf((float)(end - beg), 1.0f);
    float4 xv = ((const float4*)entity_emb)[(long)ent * 16 + ql];
    float v0 = a0 / deg + xv.x;
    float v1 = a1 / deg + xv.y;
    float v2 = a2 / deg + xv.z;
    float v3 = a3 / deg + xv.w;
    v0 = (v0 > 0.0f) ? v0 : (__expf(v0) - 1.0f);
    v1 = (v1 > 0.0f) ? v1 : (__expf(v1) - 1.0f);
    v2 = (v2 > 0.0f) ? v2 : (__expf(v2) - 1.0f);
    v3 = (v3 > 0.0f) ? v3 : (__expf(v3) - 1.0f);
    float ss = v0 * v0 + v1 * v1 + v2 * v2 + v3 * v3;
    ss += __shfl_xor(ss, 1);
    ss += __shfl_xor(ss, 2);
    ss += __shfl_xor(ss, 4);
    ss += __shfl_xor(ss, 8);
    float inv = 1.0f / fmaxf(sqrtf(ss), 1e-12f);
    if (duo == 0) {
        float r0 = v0 * inv, r1 = v1 * inv, r2 = v2 * inv, r3 = v3 * inv;
        if (getbit(node_mask, w))
            ((float4*)all_emb)[(long)w * 16 + ql] = make_float4(r0, r1, r2, r3);
        ((uint2*)all16)[(long)w * 16 + ql] =
            make_uint2((unsigned)f2bf(r0) | ((unsigned)f2bf(r1) << 16),
                       (unsigned)f2bf(r2) | ((unsigned)f2bf(r3) << 16));
    }
}

// ---------------------------------------------------------------------------
// ui_aggregate_s: TWO SAMPLE ROWS PER WAVE (half-wave transform); beg/end
// from separate arrays.
// ---------------------------------------------------------------------------
__global__ __launch_bounds__(256) void ui_aggregate_s(const int* __restrict__ beg_ui,
                                                      const int* __restrict__ end_ui,
                                                      const int* __restrict__ colrec,
                                                      const float* __restrict__ uval,
                                                      const float* __restrict__ all_emb,
                                                      const float* __restrict__ user_emb,
                                                      const unsigned short* __restrict__ all16,
                                                      const int* __restrict__ u,
                                                      const int* __restrict__ ipos,
                                                      const int* __restrict__ ineg,
                                                      float* __restrict__ final_emb, int B) {
    const uint2* a2p = (const uint2*)all16;
    int lane = threadIdx.x & 63;
    int half = lane >> 5;
    int hl   = lane & 31;
    int duo  = hl >> 4;
    int ql   = hl & 15;
    long wpair = (long)((blockIdx.x * 256 + threadIdx.x) >> 6);
    int s = (int)(wpair * 2 + half);
    if (s >= 3 * B) return;            // 3B even: whole wave exits together
    int r;
    if (s < B)          r = u[s];
    else if (s < 2 * B) r = N_USERS + ipos[s - B];
    else                r = N_USERS + ineg[s - 2 * B];

    int beg = beg_ui[r], end = end_ui[r];
    float a0 = 0.f, a1 = 0.f, a2 = 0.f, a3 = 0.f;
    float b0 = 0.f, b1 = 0.f, b2 = 0.f, b3 = 0.f;
    int p = beg;
    for (; p + 4 <= end; p += 4) {
        int   c0 = colrec[p + duo];
        int   c1 = colrec[p + 2 + duo];
        float d0 = uval[p + duo];
        float d1 = uval[p + 2 + duo];
        uint2 v0 = a2p[(long)c0 * 16 + ql];
        uint2 v1 = a2p[(long)c1 * 16 + ql];
        a0 += d0 * bf_lo(v0.x);  a1 += d0 * bf_hi(v0.x);
        a2 += d0 * bf_lo(v0.y);  a3 += d0 * bf_hi(v0.y);
        b0 += d1 * bf_lo(v1.x);  b1 += d1 * bf_hi(v1.x);
        b2 += d1 * bf_lo(v1.y);  b3 += d1 * bf_hi(v1.y);
    }
    if (p + duo < end) {
        int   c = colrec[p + duo];
        float d = uval[p + duo];
        uint2 v = a2p[(long)c * 16 + ql];
        a0 += d * bf_lo(v.x);  a1 += d * bf_hi(v.x);
        a2 += d * bf_lo(v.y);  a3 += d * bf_hi(v.y);
    }
    if (p + 2 + duo < end) {
        int   c = colrec[p + 2 + duo];
        float d = uval[p + 2 + duo];
        uint2 v = a2p[(long)c * 16 + ql];
        b0 += d * bf_lo(v.x);  b1 += d * bf_hi(v.x);
        b2 += d * bf_lo(v.y);  b3 += d * bf_hi(v.y);
    }
    a0 += b0; a1 += b1; a2 += b2; a3 += b3;
    a0 += __shfl_xor(a0, 16);
    a1 += __shfl_xor(a1, 16);
    a2 += __shfl_xor(a2, 16);
    a3 += __shfl_xor(a3, 16);
    if (duo == 0) {
        float4 ae = (r < N_USERS)
            ? ((const float4*)user_emb)[(long)r * 16 + ql]
            : ((const float4*)all_emb)[(long)r * 16 + ql];
        ((float4*)final_emb)[(long)r * 16 + ql] =
            make_float4(0.5f * (ae.x + a0), 0.5f * (ae.y + a1),
                        0.5f * (ae.z + a2), 0.5f * (ae.w + a3));
    }
}

// ---------------------------------------------------------------------------
// Epilogue (intent folded in): one wave per sample.
// ---------------------------------------------------------------------------
__global__ void final_kernel(const int* __restrict__ u, const int* __restrict__ ipos,
                             const int* __restrict__ ineg,
                             const float* __restrict__ final_emb,
                             const float* __restrict__ all_emb,
                             const float* __restrict__ rw, const float* __restrict__ rb,
                             const float* __restrict__ iw, const float* __restrict__ rel_emb,
                             float* __restrict__ out, int B) {
    __shared__ float sh_intent[128];
    if (threadIdx.x < 64) {
        int j = threadIdx.x;
        for (int k = 0; k < 2; k++) {
            float m = -1e30f;
            for (int r = 0; r < N_REL; r++) m = fmaxf(m, iw[k * N_REL + r]);
            float Z = 0.f, acc = 0.f;
            for (int r = 0; r < N_REL; r++) {
                float e = __expf(iw[k * N_REL + r] - m);
                Z += e;
                acc += e * rel_emb[r * 64 + j];
            }
            sh_intent[k * 64 + j] = acc / Z;
        }
    }
    __syncthreads();
    int lane = threadIdx.x & 63;
    int wave = (blockIdx.x * blockDim.x + threadIdx.x) >> 6;
    int nw   = (gridDim.x * blockDim.x) >> 6;
    for (int b = wave; b < B; b += nw) {
        int uu = u[b];
        float up = final_emb[(long)uu * 64 + lane];
        float l0 = up * rw[lane];
        float l1 = up * rw[64 + lane];
        #pragma unroll
        for (int o = 32; o; o >>= 1) {
            l0 += __shfl_xor(l0, o);
            l1 += __shfl_xor(l1, o);
        }
        l0 += rb[0]; l1 += rb[1];
        float m  = fmaxf(l0, l1);
        float e0 = __expf(l0 - m), e1 = __expf(l1 - m);
        float inv = 1.0f / (e0 + e1);
        float p0 = e0 * inv, p1 = e1 * inv;
        float ue = up + p0 * sh_intent[lane] + p1 * sh_intent[64 + lane];

        int it = ipos[b];
        long rr = (long)(N_USERS + it) * 64 + lane;
        float ie = final_emb[rr] + all_emb[rr];
        float dp = ue * ie;
        #pragma unroll
        for (int o = 32; o; o >>= 1) dp += __shfl_xor(dp, o);
        if (lane == 0) out[b] = dp;

        it = ineg[b];
        rr = (long)(N_USERS + it) * 64 + lane;
        ie = final_emb[rr] + all_emb[rr];
        dp = ue * ie;
        #pragma unroll
        for (int o = 32; o; o >>= 1) dp += __shfl_xor(dp, o);
        if (lane == 0) out[B + b] = dp;
    }
}

extern "C" void kernel_launch(void* const* d_in, const int* in_sizes, int n_in,
                              void* d_out, int out_size, void* d_ws, size_t ws_size,
                              hipStream_t stream) {
    const int*   u          = (const int*)  d_in[0];
    const int*   ipos       = (const int*)  d_in[1];
    const int*   ineg       = (const int*)  d_in[2];
    const float* user_emb   = (const float*)d_in[3];
    const float* entity_emb = (const float*)d_in[4];
    const float* rel_emb    = (const float*)d_in[5];
    const float* iw         = (const float*)d_in[6];
    const float* rw         = (const float*)d_in[7];
    const float* rb         = (const float*)d_in[8];
    const float* kgw        = (const float*)d_in[9];
    const float* ui_vals    = (const float*)d_in[10];
    const int*   i2e        = (const int*)  d_in[11];
    const int*   kg_src     = (const int*)  d_in[12];
    const int*   kg_dst     = (const int*)  d_in[13];
    const int*   kg_rel     = (const int*)  d_in[14];
    const int*   ui_row     = (const int*)  d_in[15];
    const int*   ui_col     = (const int*)  d_in[16];
    float*       out        = (float*)d_out;

    int B    = in_sizes[0];
    int e_kg = in_sizes[12];
    int e_ui = in_sizes[15];

    // ---------------- workspace layout (bytes) ----------------
    // Fixed-capacity buckets: kgrec = NB_KG*CAPK*4 = 6406144 (8MB region);
    // end arrays live in kgrec's tail slack. uirec/uval = NB_UI*CAPU*4 =
    // 3600384 each (4MB regions). High-water mark unchanged from R8.
    char* ws = (char*)d_ws;
    unsigned short* y16       = (unsigned short*)(ws + 0);        // 25.6 MB
    float*          all_emb   = (float*)(ws + 25600000);          // 38.4 MB
    unsigned short* all16     = (unsigned short*)(ws + 64000000); // 19.2 MB
    float*          final_emb = (float*)(ws + 83200000);          // 38.4 MB (sparse use)
    unsigned int*   kgrec     = (unsigned int*)(ws + 121600000);  // 6.4 MB used
    int*            end_kg    = (int*)(ws + 128006144);           // 800000 B
    int*            end_ui    = (int*)(ws + 128806144);           // 600000 B (ends 129406144)
    int*            uirec     = (int*)(ws + 129600000);           // 3.6 MB used
    float*          uval      = (float*)(ws + 133600000);         // 3.6 MB used
    int*            beg_kg    = (int*)(ws + 137600000);           // 800000 B
    int*            beg_ui    = (int*)(ws + 138400256);           // 600000 B
    unsigned*       ent_mask  = (unsigned*)(ws + 139000512);      // 25088 B (200K bits)
    unsigned*       node_mask = (unsigned*)(ws + 139025600);      // 18752 B (150K bits)
    int*            bcur      = (int*)(ws + 139608704);           // 977 ints
    float2*         gateg     = (float2*)(ws + 139612672);        // 8 KB gate table

    hipMemsetAsync(ent_mask, 0, 25088 + 18752, stream);   // masks contiguous
    build_masks<<<512, 256, 0, stream>>>(i2e, u, ipos, ineg, rel_emb, gateg,
                                         ent_mask, node_mask, bcur, B);
    // Fused + interleaved: scatter (bid%3==0) || ent_matmul (others)
    mm_scatter <<<FUSE_GRID, 512, 0, stream>>>(
        entity_emb, kgw, y16, N_ENT,
        kg_src, kg_dst, kg_rel, ui_row, ui_col, ui_vals,
        ent_mask, node_mask, bcur, kgrec, uirec, uval, e_kg, e_ui);
    bucket_finalize<<<NB_TOT, 256, 0, stream>>>(bcur, kgrec, uirec, uval,
                                                beg_kg, end_kg, beg_ui, end_ui);
    {   // two nodes per wave
        int nwaves = (N_NODES + 1) / 2;
        int nblk   = (nwaves * 64 + 255) / 256;
        kgagg_build<<<nblk, 256, 0, stream>>>(
            beg_kg, end_kg, kgrec, y16, entity_emb, user_emb, i2e,
            (const float4*)gateg, node_mask, all_emb, all16);
    }
    {   // two sample rows per wave
        int nwaves = (3 * B + 1) / 2;
        int nblk   = (nwaves * 64 + 255) / 256;
        ui_aggregate_s<<<nblk, 256, 0, stream>>>(
            beg_ui, end_ui, uirec, uval, all_emb, user_emb, all16,
            u, ipos, ineg, final_emb, B);
    }
    final_kernel<<<256, 256, 0, stream>>>(u, ipos, ineg, final_emb, all_emb,
                                          rw, rb, iw, rel_emb, out, B);
}

// Round 11
// 273.075 us; speedup vs baseline: 1.4724x; 1.0246x over previous
//
#include <hip/hip_runtime.h>
#include <math.h>

#define N_USERS 50000
#define N_ITEMS 100000
#define N_ENT   200000
#define N_NODES (N_USERS + N_ITEMS)
#define N_REL   32
#define DIM     64

#define NB_KG  391          // KG buckets: dst>>9 (512 keys each)
#define NB_UI  586          // UI buckets: row>>8 (256 keys each)
#define NB_TOT (NB_KG + NB_UI)   // 977
#define CAPK   4096         // fixed capacity per KG bucket (max kept ~2700)
#define CAPU   1536         // fixed capacity per UI bucket (max kept ~850)
#define NMMTILE 1563        // ceil(200000/128) matmul tiles
#define NSCAT  768          // scatter blocks (prefix — R8 measured best)
#define NCPY   208          // user bf16-copy blocks (third fused role)
#define FUSE_GRID (NSCAT + NMMTILE + NCPY)

__device__ __forceinline__ unsigned short f2bf(float f) {   // RNE f32->bf16
    unsigned u = __float_as_uint(f);
    u += 0x7FFFu + ((u >> 16) & 1u);
    return (unsigned short)(u >> 16);
}
__device__ __forceinline__ float bf_lo(unsigned v) { return __uint_as_float(v << 16); }
__device__ __forceinline__ float bf_hi(unsigned v) { return __uint_as_float(v & 0xFFFF0000u); }
__device__ __forceinline__ int getbit(const unsigned* m, int i) {
    return (m[i >> 5] >> (i & 31)) & 1;
}

// ---------------------------------------------------------------------------
// build_masks: membership bitmaps + bcur init (fixed-capacity bucket bases)
// + gate table (block 0).
// ---------------------------------------------------------------------------
__global__ __launch_bounds__(256) void build_masks(const int* __restrict__ i2e,
                                                   const int* __restrict__ u,
                                                   const int* __restrict__ ipos,
                                                   const int* __restrict__ ineg,
                                                   const float* __restrict__ rel_emb,
                                                   float2* __restrict__ gateg,
                                                   unsigned* __restrict__ ent_mask,
                                                   unsigned* __restrict__ node_mask,
                                                   int* __restrict__ bcur,
                                                   int B) {
    int t = blockIdx.x * 256 + threadIdx.x;
    int stride = gridDim.x * 256;
    for (int i = threadIdx.x; i < NB_TOT; i += 256)          // same-value benign race
        bcur[i] = (i < NB_KG) ? i * CAPK : (i - NB_KG) * CAPU;
    if (blockIdx.x == 0) {
        for (int idx = threadIdx.x; idx < N_REL * 32; idx += 256) {
            int rel = idx >> 5, hl2 = idx & 31;
            float g0 = 1.0f / (1.0f + __expf(-rel_emb[rel * 64 + 2 * hl2]));
            float g1 = 1.0f / (1.0f + __expf(-rel_emb[rel * 64 + 2 * hl2 + 1]));
            gateg[idx] = make_float2(g0, g1);
        }
    }
    for (int i = t; i < N_ITEMS; i += stride) {
        int e = i2e[i];
        atomicOr(&ent_mask[e >> 5], 1u << (e & 31));
    }
    for (int i = t; i < 3 * B; i += stride) {
        int r = (i < B) ? u[i]
              : (i < 2 * B) ? N_USERS + ipos[i - B]
                            : N_USERS + ineg[i - 2 * B];
        atomicOr(&node_mask[r >> 5], 1u << (r & 31));
    }
}

// ---------------------------------------------------------------------------
// mm_scatter: FUSED dispatch, THREE roles, PREFIX mapping (R10: the %3
// interleave measured WORSE — 72 vs 67us — co-residency stretched the
// latency-bound scatter; phased prefix is the measured-best config):
//   blocks [0, NSCAT)            : edge scatter into fixed-capacity buckets
//   blocks [NSCAT, NSCAT+NMMTILE): ent_matmul tiles (swizzled 48KB LDS)
//   blocks [NSCAT+NMMTILE, ...)  : user bf16-copy (user_emb -> all16), moved
//                                  out of kgagg_build (pure BW, hides in
//                                  this dispatch's 15%-HBM slack)
// Matmul FMA order k-ascending per output -> BIT-IDENTICAL numerics; copy
// produces identical bf16 values as kgagg's old user branch.
// ---------------------------------------------------------------------------
__global__ __launch_bounds__(512) void mm_scatter(const float* __restrict__ x,
                                                  const float* __restrict__ w,
                                                  unsigned short* __restrict__ y16,
                                                  int n_ent,
                                                  const int* __restrict__ kg_src,
                                                  const int* __restrict__ kg_dst,
                                                  const int* __restrict__ kg_rel,
                                                  const int* __restrict__ ui_row,
                                                  const int* __restrict__ ui_col,
                                                  const float* __restrict__ ui_vals,
                                                  const unsigned* __restrict__ ent_mask,
                                                  const unsigned* __restrict__ node_mask,
                                                  int* __restrict__ bcur,
                                                  unsigned int* __restrict__ kgrec,
                                                  int* __restrict__ uirec,
                                                  float* __restrict__ uval,
                                                  const float* __restrict__ user_emb,
                                                  unsigned short* __restrict__ all16,
                                                  int e_kg, int e_ui) {
    __shared__ __align__(16) char smem[49152];
    int tid = threadIdx.x;
    int bid = blockIdx.x;

    if (bid < NSCAT) {
        // ---------------- scatter branch ----------------
        int* h     = (int*)smem;
        int* lbase = h + NB_TOT;
        int n = e_kg + e_ui;
        int nchunks = (n + 4095) >> 12;
        for (int c = bid; c < nchunks; c += NSCAT) {
            int base = c << 12;
            for (int i = tid; i < NB_TOT; i += 512) h[i] = 0;
            __syncthreads();
            unsigned int rec[8];
            float val[8];
            int bk[8];
            #pragma unroll
            for (int j = 0; j < 8; j++) {
                int e = base + j * 512 + tid;
                bk[j] = -1;
                if (e < n) {
                    if (e < e_kg) {
                        int d = kg_dst[e];
                        if (getbit(ent_mask, d)) {
                            bk[j]  = d >> 9;
                            rec[j] = (unsigned int)kg_src[e]
                                     | ((unsigned int)kg_rel[e] << 18)
                                     | ((unsigned int)(d & 511) << 23);
                            atomicAdd(&h[bk[j]], 1);
                        }
                    } else {
                        int i2 = e - e_kg;
                        int r  = ui_row[i2];
                        if (getbit(node_mask, r)) {
                            bk[j]  = NB_KG + (r >> 8);
                            rec[j] = (unsigned int)ui_col[i2]
                                     | ((unsigned int)(r & 255) << 18);
                            val[j] = ui_vals[i2];
                            atomicAdd(&h[bk[j]], 1);
                        }
                    }
                }
            }
            __syncthreads();
            for (int i = tid; i < NB_TOT; i += 512) {
                int cc = h[i];
                lbase[i] = cc ? atomicAdd(&bcur[i], cc) : 0;
            }
            __syncthreads();
            #pragma unroll
            for (int j = 0; j < 8; j++) {
                if (bk[j] >= 0) {
                    int pos = atomicAdd(&lbase[bk[j]], 1);
                    if (bk[j] < NB_KG) {
                        if (pos < (bk[j] + 1) * CAPK) kgrec[pos] = rec[j];
                    } else {
                        int bu = bk[j] - NB_KG;
                        if (pos < (bu + 1) * CAPU) { uirec[pos] = (int)rec[j]; uval[pos] = val[j]; }
                    }
                }
            }
            __syncthreads();
        }
        return;
    }

    if (bid >= NSCAT + NMMTILE) {
        // ---------------- user bf16-copy branch ----------------
        int cid = bid - NSCAT - NMMTILE;
        const float4* ue4 = (const float4*)user_emb;
        uint2* a2 = (uint2*)all16;
        int total = N_USERS * 16;
        for (int i = cid * 512 + tid; i < total; i += NCPY * 512) {
            float4 v = ue4[i];
            a2[i] = make_uint2((unsigned)f2bf(v.x) | ((unsigned)f2bf(v.y) << 16),
                               (unsigned)f2bf(v.z) | ((unsigned)f2bf(v.w) << 16));
        }
        return;
    }

    // ---------------- matmul branch ----------------
    int mtile = bid - NSCAT;
    float (*xt)[128] = (float (*)[128])smem;            // 32768 B
    float (*wt)[64]  = (float (*)[64])(smem + 32768);   // 16384 B
    int base = mtile * 128;

    #pragma unroll
    for (int q = 0; q < 2; q++) {
        int idx = q * 512 + tid;          // 1024 float4 of w
        int j = idx >> 4, k4 = idx & 15;
        int s0 = (k4 << 2) & 28;          // sigma for rows 4k4..4k4+3
        float4 v = ((const float4*)w)[idx];
        wt[4 * k4 + 0][j ^ s0] = v.x;
        wt[4 * k4 + 1][j ^ s0] = v.y;
        wt[4 * k4 + 2][j ^ s0] = v.z;
        wt[4 * k4 + 3][j ^ s0] = v.w;
    }
    #pragma unroll
    for (int q = 0; q < 4; q++) {
        int idx = q * 512 + tid;          // 2048 float4 of x
        int r = idx >> 4, k4 = idx & 15;
        int gr = base + r;
        int s0 = (k4 << 2) & 28;
        if (gr < n_ent) {
            float4 v = ((const float4*)x)[(long)gr * 16 + k4];
            xt[4 * k4 + 0][r ^ s0] = v.x;
            xt[4 * k4 + 1][r ^ s0] = v.y;
            xt[4 * k4 + 2][r ^ s0] = v.z;
            xt[4 * k4 + 3][r ^ s0] = v.w;
        }
    }
    __syncthreads();

    int j0 = (tid & 7) * 8;               // 8 output cols
    int r0 = (tid >> 3) * 2;              // 2 output rows (0..126)
    float acc[2][8];
    #pragma unroll
    for (int i = 0; i < 2; i++)
        #pragma unroll
        for (int j = 0; j < 8; j++) acc[i][j] = 0.f;

    #pragma unroll 4
    for (int k = 0; k < 64; k++) {
        int s = k & 28;
        float2 xa = *(const float2*)&xt[k][r0 ^ s];
        float4 wa = *(const float4*)&wt[k][j0 ^ s];
        float4 wb = *(const float4*)&wt[k][(j0 + 4) ^ s];
        float xr[2] = {xa.x, xa.y};
        float wr[8] = {wa.x, wa.y, wa.z, wa.w, wb.x, wb.y, wb.z, wb.w};
        #pragma unroll
        for (int i = 0; i < 2; i++)
            #pragma unroll
            for (int j = 0; j < 8; j++)
                acc[i][j] += xr[i] * wr[j];
    }

    #pragma unroll
    for (int i = 0; i < 2; i++) {
        int gr = base + r0 + i;
        if (gr < n_ent) {
            uint4 o;
            o.x = (unsigned)f2bf(acc[i][0]) | ((unsigned)f2bf(acc[i][1]) << 16);
            o.y = (unsigned)f2bf(acc[i][2]) | ((unsigned)f2bf(acc[i][3]) << 16);
            o.z = (unsigned)f2bf(acc[i][4]) | ((unsigned)f2bf(acc[i][5]) << 16);
            o.w = (unsigned)f2bf(acc[i][6]) | ((unsigned)f2bf(acc[i][7]) << 16);
            *(uint4*)&y16[(long)gr * 64 + j0] = o;
        }
    }
}

// ---------------------------------------------------------------------------
// bucket_finalize: one block per bucket, fixed-capacity regions. Emits
// beg[]/end[] arrays + sorted recs in place.
// ---------------------------------------------------------------------------
__global__ __launch_bounds__(256) void bucket_finalize(const int* __restrict__ bcur,
                                                       unsigned int* __restrict__ kgrec,
                                                       int* __restrict__ uirec,
                                                       float* __restrict__ uval,
                                                       int* __restrict__ beg_kg,
                                                       int* __restrict__ end_kg,
                                                       int* __restrict__ beg_ui,
                                                       int* __restrict__ end_ui) {
    __shared__ unsigned int rec[CAPK];
    __shared__ float fval[CAPU];
    __shared__ int hist[512];
    bool iskg = blockIdx.x < NB_KG;
    int  b    = iskg ? blockIdx.x : blockIdx.x - NB_KG;
    int base  = iskg ? b * CAPK : b * CAPU;
    int cap   = iskg ? CAPK : CAPU;
    int ne    = min(bcur[blockIdx.x] - base, cap);
    int key_base = iskg ? (b << 9) : (b << 8);
    int nkeys = iskg ? min(512, N_ENT - key_base) : min(256, N_NODES - key_base);
    int SH = iskg ? 23 : 18;
    int tid = threadIdx.x;

    for (int i = tid; i < ne; i += 256) {
        if (iskg) rec[i] = kgrec[base + i];
        else { rec[i] = (unsigned int)uirec[base + i]; fval[i] = uval[base + i]; }
    }
    for (int i = tid; i < 512; i += 256) hist[i] = 0;
    __syncthreads();
    for (int i = tid; i < ne; i += 256)
        atomicAdd(&hist[rec[i] >> SH], 1);
    __syncthreads();
    int i0 = tid, i1 = tid + 256;
    int v0 = hist[i0], v1 = hist[i1];
    __syncthreads();
    for (int o = 1; o < 512; o <<= 1) {
        int a0 = (i0 >= o) ? hist[i0 - o] : 0;
        int a1 = (i1 >= o) ? hist[i1 - o] : 0;
        __syncthreads();
        hist[i0] += a0; hist[i1] += a1;
        __syncthreads();
    }
    int e0 = hist[i0] - v0, e1 = hist[i1] - v1;
    __syncthreads();
    hist[i0] = e0; hist[i1] = e1;
    int* begg = iskg ? beg_kg : beg_ui;
    int* endg = iskg ? end_kg : end_ui;
    if (i0 < nkeys) { begg[key_base + i0] = base + e0; endg[key_base + i0] = base + e0 + v0; }
    if (i1 < nkeys) { begg[key_base + i1] = base + e1; endg[key_base + i1] = base + e1 + v1; }
    __syncthreads();
    for (int i = tid; i < ne; i += 256) {
        unsigned int r = rec[i];
        int k = r >> SH;
        int slot = atomicAdd(&hist[k], 1);
        if (iskg) kgrec[base + slot] = r & 0x7FFFFFu;
        else      { uirec[base + slot] = (int)(r & 0x3FFFFu); uval[base + slot] = fval[i]; }
    }
}

// ---------------------------------------------------------------------------
// kgagg_build: ITEM-ONLY (user copy moved into mm_scatter). TWO ITEMS PER
// WAVE, one per half-wave. beg/end from separate arrays. f32 all_emb written
// only for node_mask-marked item rows.
// ---------------------------------------------------------------------------
__global__ __launch_bounds__(256) void kgagg_build(const int* __restrict__ beg_kg,
                                                   const int* __restrict__ end_kg,
                                                   const unsigned int* __restrict__ packed,
                                                   const unsigned short* __restrict__ y16,
                                                   const float* __restrict__ entity_emb,
                                                   const int* __restrict__ i2e,
                                                   const float4* __restrict__ gate4,
                                                   const unsigned* __restrict__ node_mask,
                                                   float* __restrict__ all_emb,
                                                   unsigned short* __restrict__ all16) {
    int lane = threadIdx.x & 63;
    int half = lane >> 5;          // which item of the pair
    int hl   = lane & 31;
    int duo  = hl >> 4;            // edge slot within half
    int ql   = hl & 15;            // dims 4ql..4ql+3
    long wpair = (long)((blockIdx.x * 256 + threadIdx.x) >> 6);
    int it = (int)(wpair * 2 + half);
    if (it >= N_ITEMS) return;     // N_ITEMS even: whole wave exits together
    int w = N_USERS + it;

    int ent = i2e[it];             // half-uniform (broadcast load)
    const uint2* y2 = (const uint2*)y16;
    int beg = beg_kg[ent], end = end_kg[ent];
    float a0 = 0.f, a1 = 0.f, a2 = 0.f, a3 = 0.f;
    float b0 = 0.f, b1 = 0.f, b2 = 0.f, b3 = 0.f;
    int p = beg;
    for (; p + 4 <= end; p += 4) {     // 4 edges per half per iter
        unsigned pk0 = packed[p + duo];
        unsigned pk1 = packed[p + 2 + duo];
        uint2 v0 = y2[(long)(pk0 & 0x3FFFF) * 16 + ql];
        uint2 v1 = y2[(long)(pk1 & 0x3FFFF) * 16 + ql];
        float4 g0 = gate4[(pk0 >> 18) * 16 + ql];
        float4 g1 = gate4[(pk1 >> 18) * 16 + ql];
        a0 += bf_lo(v0.x) * g0.x;  a1 += bf_hi(v0.x) * g0.y;
        a2 += bf_lo(v0.y) * g0.z;  a3 += bf_hi(v0.y) * g0.w;
        b0 += bf_lo(v1.x) * g1.x;  b1 += bf_hi(v1.x) * g1.y;
        b2 += bf_lo(v1.y) * g1.z;  b3 += bf_hi(v1.y) * g1.w;
    }
    if (p + duo < end) {               // tail edges p..p+1
        unsigned pk = packed[p + duo];
        uint2 v = y2[(long)(pk & 0x3FFFF) * 16 + ql];
        float4 g = gate4[(pk >> 18) * 16 + ql];
        a0 += bf_lo(v.x) * g.x;  a1 += bf_hi(v.x) * g.y;
        a2 += bf_lo(v.y) * g.z;  a3 += bf_hi(v.y) * g.w;
    }
    if (p + 2 + duo < end) {           // tail edge p+2 (p+3 impossible)
        unsigned pk = packed[p + 2 + duo];
        uint2 v = y2[(long)(pk & 0x3FFFF) * 16 + ql];
        float4 g = gate4[(pk >> 18) * 16 + ql];
        b0 += bf_lo(v.x) * g.x;  b1 += bf_hi(v.x) * g.y;
        b2 += bf_lo(v.y) * g.z;  b3 += bf_hi(v.y) * g.w;
    }
    a0 += b0; a1 += b1; a2 += b2; a3 += b3;
    a0 += __shfl_xor(a0, 16);          // merge the two duo slots (within half)
    a1 += __shfl_xor(a1, 16);
    a2 += __shfl_xor(a2, 16);
    a3 += __shfl_xor(a3, 16);

    float deg = fmaxf((float)(end - beg), 1.0f);
    float4 xv = ((const float4*)entity_emb)[(long)ent * 16 + ql];
    float v0 = a0 / deg + xv.x;
    float v1 = a1 / deg + xv.y;
    float v2 = a2 / deg + xv.z;
    float v3 = a3 / deg + xv.w;
    v0 = (v0 > 0.0f) ? v0 : (__expf(v0) - 1.0f);
    v1 = (v1 > 0.0f) ? v1 : (__expf(v1) - 1.0f);
    v2 = (v2 > 0.0f) ? v2 : (__expf(v2) - 1.0f);
    v3 = (v3 > 0.0f) ? v3 : (__expf(v3) - 1.0f);
    float ss = v0 * v0 + v1 * v1 + v2 * v2 + v3 * v3;
    ss += __shfl_xor(ss, 1);
    ss += __shfl_xor(ss, 2);
    ss += __shfl_xor(ss, 4);
    ss += __shfl_xor(ss, 8);
    float inv = 1.0f / fmaxf(sqrtf(ss), 1e-12f);
    if (duo == 0) {
        float r0 = v0 * inv, r1 = v1 * inv, r2 = v2 * inv, r3 = v3 * inv;
        if (getbit(node_mask, w))
            ((float4*)all_emb)[(long)w * 16 + ql] = make_float4(r0, r1, r2, r3);
        ((uint2*)all16)[(long)w * 16 + ql] =
            make_uint2((unsigned)f2bf(r0) | ((unsigned)f2bf(r1) << 16),
                       (unsigned)f2bf(r2) | ((unsigned)f2bf(r3) << 16));
    }
}

// ---------------------------------------------------------------------------
// ui_aggregate_s: TWO SAMPLE ROWS PER WAVE (half-wave transform); beg/end
// from separate arrays.
// ---------------------------------------------------------------------------
__global__ __launch_bounds__(256) void ui_aggregate_s(const int* __restrict__ beg_ui,
                                                      const int* __restrict__ end_ui,
                                                      const int* __restrict__ colrec,
                                                      const float* __restrict__ uval,
                                                      const float* __restrict__ all_emb,
                                                      const float* __restrict__ user_emb,
                                                      const unsigned short* __restrict__ all16,
                                                      const int* __restrict__ u,
                                                      const int* __restrict__ ipos,
                                                      const int* __restrict__ ineg,
                                                      float* __restrict__ final_emb, int B) {
    const uint2* a2p = (const uint2*)all16;
    int lane = threadIdx.x & 63;
    int half = lane >> 5;
    int hl   = lane & 31;
    int duo  = hl >> 4;
    int ql   = hl & 15;
    long wpair = (long)((blockIdx.x * 256 + threadIdx.x) >> 6);
    int s = (int)(wpair * 2 + half);
    if (s >= 3 * B) return;            // 3B even: whole wave exits together
    int r;
    if (s < B)          r = u[s];
    else if (s < 2 * B) r = N_USERS + ipos[s - B];
    else                r = N_USERS + ineg[s - 2 * B];

    int beg = beg_ui[r], end = end_ui[r];
    float a0 = 0.f, a1 = 0.f, a2 = 0.f, a3 = 0.f;
    float b0 = 0.f, b1 = 0.f, b2 = 0.f, b3 = 0.f;
    int p = beg;
    for (; p + 4 <= end; p += 4) {
        int   c0 = colrec[p + duo];
        int   c1 = colrec[p + 2 + duo];
        float d0 = uval[p + duo];
        float d1 = uval[p + 2 + duo];
        uint2 v0 = a2p[(long)c0 * 16 + ql];
        uint2 v1 = a2p[(long)c1 * 16 + ql];
        a0 += d0 * bf_lo(v0.x);  a1 += d0 * bf_hi(v0.x);
        a2 += d0 * bf_lo(v0.y);  a3 += d0 * bf_hi(v0.y);
        b0 += d1 * bf_lo(v1.x);  b1 += d1 * bf_hi(v1.x);
        b2 += d1 * bf_lo(v1.y);  b3 += d1 * bf_hi(v1.y);
    }
    if (p + duo < end) {
        int   c = colrec[p + duo];
        float d = uval[p + duo];
        uint2 v = a2p[(long)c * 16 + ql];
        a0 += d * bf_lo(v.x);  a1 += d * bf_hi(v.x);
        a2 += d * bf_lo(v.y);  a3 += d * bf_hi(v.y);
    }
    if (p + 2 + duo < end) {
        int   c = colrec[p + 2 + duo];
        float d = uval[p + 2 + duo];
        uint2 v = a2p[(long)c * 16 + ql];
        b0 += d * bf_lo(v.x);  b1 += d * bf_hi(v.x);
        b2 += d * bf_lo(v.y);  b3 += d * bf_hi(v.y);
    }
    a0 += b0; a1 += b1; a2 += b2; a3 += b3;
    a0 += __shfl_xor(a0, 16);
    a1 += __shfl_xor(a1, 16);
    a2 += __shfl_xor(a2, 16);
    a3 += __shfl_xor(a3, 16);
    if (duo == 0) {
        float4 ae = (r < N_USERS)
            ? ((const float4*)user_emb)[(long)r * 16 + ql]
            : ((const float4*)all_emb)[(long)r * 16 + ql];
        ((float4*)final_emb)[(long)r * 16 + ql] =
            make_float4(0.5f * (ae.x + a0), 0.5f * (ae.y + a1),
                        0.5f * (ae.z + a2), 0.5f * (ae.w + a3));
    }
}

// ---------------------------------------------------------------------------
// Epilogue (intent folded in): one wave per sample.
// ---------------------------------------------------------------------------
__global__ void final_kernel(const int* __restrict__ u, const int* __restrict__ ipos,
                             const int* __restrict__ ineg,
                             const float* __restrict__ final_emb,
                             const float* __restrict__ all_emb,
                             const float* __restrict__ rw, const float* __restrict__ rb,
                             const float* __restrict__ iw, const float* __restrict__ rel_emb,
                             float* __restrict__ out, int B) {
    __shared__ float sh_intent[128];
    if (threadIdx.x < 64) {
        int j = threadIdx.x;
        for (int k = 0; k < 2; k++) {
            float m = -1e30f;
            for (int r = 0; r < N_REL; r++) m = fmaxf(m, iw[k * N_REL + r]);
            float Z = 0.f, acc = 0.f;
            for (int r = 0; r < N_REL; r++) {
                float e = __expf(iw[k * N_REL + r] - m);
                Z += e;
                acc += e * rel_emb[r * 64 + j];
            }
            sh_intent[k * 64 + j] = acc / Z;
        }
    }
    __syncthreads();
    int lane = threadIdx.x & 63;
    int wave = (blockIdx.x * blockDim.x + threadIdx.x) >> 6;
    int nw   = (gridDim.x * blockDim.x) >> 6;
    for (int b = wave; b < B; b += nw) {
        int uu = u[b];
        float up = final_emb[(long)uu * 64 + lane];
        float l0 = up * rw[lane];
        float l1 = up * rw[64 + lane];
        #pragma unroll
        for (int o = 32; o; o >>= 1) {
            l0 += __shfl_xor(l0, o);
            l1 += __shfl_xor(l1, o);
        }
        l0 += rb[0]; l1 += rb[1];
        float m  = fmaxf(l0, l1);
        float e0 = __expf(l0 - m), e1 = __expf(l1 - m);
        float inv = 1.0f / (e0 + e1);
        float p0 = e0 * inv, p1 = e1 * inv;
        float ue = up + p0 * sh_intent[lane] + p1 * sh_intent[64 + lane];

        int it = ipos[b];
        long rr = (long)(N_USERS + it) * 64 + lane;
        float ie = final_emb[rr] + all_emb[rr];
        float dp = ue * ie;
        #pragma unroll
        for (int o = 32; o; o >>= 1) dp += __shfl_xor(dp, o);
        if (lane == 0) out[b] = dp;

        it = ineg[b];
        rr = (long)(N_USERS + it) * 64 + lane;
        ie = final_emb[rr] + all_emb[rr];
        dp = ue * ie;
        #pragma unroll
        for (int o = 32; o; o >>= 1) dp += __shfl_xor(dp, o);
        if (lane == 0) out[B + b] = dp;
    }
}

extern "C" void kernel_launch(void* const* d_in, const int* in_sizes, int n_in,
                              void* d_out, int out_size, void* d_ws, size_t ws_size,
                              hipStream_t stream) {
    const int*   u          = (const int*)  d_in[0];
    const int*   ipos       = (const int*)  d_in[1];
    const int*   ineg       = (const int*)  d_in[2];
    const float* user_emb   = (const float*)d_in[3];
    const float* entity_emb = (const float*)d_in[4];
    const float* rel_emb    = (const float*)d_in[5];
    const float* iw         = (const float*)d_in[6];
    const float* rw         = (const float*)d_in[7];
    const float* rb         = (const float*)d_in[8];
    const float* kgw        = (const float*)d_in[9];
    const float* ui_vals    = (const float*)d_in[10];
    const int*   i2e        = (const int*)  d_in[11];
    const int*   kg_src     = (const int*)  d_in[12];
    const int*   kg_dst     = (const int*)  d_in[13];
    const int*   kg_rel     = (const int*)  d_in[14];
    const int*   ui_row     = (const int*)  d_in[15];
    const int*   ui_col     = (const int*)  d_in[16];
    float*       out        = (float*)d_out;

    int B    = in_sizes[0];
    int e_kg = in_sizes[12];
    int e_ui = in_sizes[15];

    // ---------------- workspace layout (bytes) ----------------
    char* ws = (char*)d_ws;
    unsigned short* y16       = (unsigned short*)(ws + 0);        // 25.6 MB
    float*          all_emb   = (float*)(ws + 25600000);          // 38.4 MB
    unsigned short* all16     = (unsigned short*)(ws + 64000000); // 19.2 MB
    float*          final_emb = (float*)(ws + 83200000);          // 38.4 MB (sparse use)
    unsigned int*   kgrec     = (unsigned int*)(ws + 121600000);  // 6.4 MB used
    int*            end_kg    = (int*)(ws + 128006144);           // 800000 B
    int*            end_ui    = (int*)(ws + 128806144);           // 600000 B
    int*            uirec     = (int*)(ws + 129600000);           // 3.6 MB used
    float*          uval      = (float*)(ws + 133600000);         // 3.6 MB used
    int*            beg_kg    = (int*)(ws + 137600000);           // 800000 B
    int*            beg_ui    = (int*)(ws + 138400256);           // 600000 B
    unsigned*       ent_mask  = (unsigned*)(ws + 139000512);      // 25088 B (200K bits)
    unsigned*       node_mask = (unsigned*)(ws + 139025600);      // 18752 B (150K bits)
    int*            bcur      = (int*)(ws + 139608704);           // 977 ints
    float2*         gateg     = (float2*)(ws + 139612672);        // 8 KB gate table

    hipMemsetAsync(ent_mask, 0, 25088 + 18752, stream);   // masks contiguous
    build_masks<<<512, 256, 0, stream>>>(i2e, u, ipos, ineg, rel_emb, gateg,
                                         ent_mask, node_mask, bcur, B);
    // Fused: scatter [0,768) | matmul [768,2331) | user-copy [2331,2539)
    mm_scatter <<<FUSE_GRID, 512, 0, stream>>>(
        entity_emb, kgw, y16, N_ENT,
        kg_src, kg_dst, kg_rel, ui_row, ui_col, ui_vals,
        ent_mask, node_mask, bcur, kgrec, uirec, uval,
        user_emb, all16, e_kg, e_ui);
    bucket_finalize<<<NB_TOT, 256, 0, stream>>>(bcur, kgrec, uirec, uval,
                                                beg_kg, end_kg, beg_ui, end_ui);
    {   // item-only, two items per wave
        int nwaves = N_ITEMS / 2;
        int nblk   = (nwaves * 64 + 255) / 256;    // 12500
        kgagg_build<<<nblk, 256, 0, stream>>>(
            beg_kg, end_kg, kgrec, y16, entity_emb, i2e,
            (const float4*)gateg, node_mask, all_emb, all16);
    }
    {   // two sample rows per wave
        int nwaves = (3 * B + 1) / 2;
        int nblk   = (nwaves * 64 + 255) / 256;
        ui_aggregate_s<<<nblk, 256, 0, stream>>>(
            beg_ui, end_ui, uirec, uval, all_emb, user_emb, all16,
            u, ipos, ineg, final_emb, B);
    }
    final_kernel<<<256, 256, 0, stream>>>(u, ipos, ineg, final_emb, all_emb,
                                          rw, rb, iw, rel_emb, out, B);
}